// Round 1
// baseline (597.684 us; speedup 1.0000x reference)
//
#include <hip/hip_runtime.h>

// ---------------------------------------------------------------------------
// TransformerBlock on MI355X (gfx950), bf16 MFMA internal compute.
// B=4 T=2048 C=1024 H=16 D=64 FF=4096. All fp32 I/O; bf16 internally.
//
// Pipeline:
//   transpose_cvt x6  : fp32 weights -> bf16 B^T [N][K] (qkv packed N=3072)
//   ln_bf16           : h = LN(x) -> bf16
//   gemm_bt<0>        : QKV = h * Wqkv^T  -> scatter to Q/K/V [B,H,T,D] bf16
//   attn_kernel       : causal flash attention -> O [B,T,C] bf16
//   gemm_bt<1>        : x1 = O*Wp + b_proj + x          (fp32)
//   ln_bf16           : h2 = LN(x1) -> bf16
//   gemm_bt<2>        : ff = relu(h2*W1 + b1)           (bf16)
//   gemm_bt<1>        : out = ff*W2 + b2 + x1           (fp32 -> d_out)
// ---------------------------------------------------------------------------

#define DEVI __device__ __forceinline__

typedef float  f32x4  __attribute__((ext_vector_type(4)));
typedef __bf16 bf16x8 __attribute__((ext_vector_type(8)));
typedef short  s16x8  __attribute__((ext_vector_type(8)));
typedef unsigned short u16;

DEVI u16 f2bf(float f) {            // RNE fp32 -> bf16 bits
    unsigned u = __builtin_bit_cast(unsigned, f);
    u += 0x7fffu + ((u >> 16) & 1u);
    return (u16)(u >> 16);
}

DEVI void gload_lds16(const void* g, void* l) {
    // async global->LDS, 16B/lane, dest = wave-uniform base + lane*16
    __builtin_amdgcn_global_load_lds(
        (__attribute__((address_space(1))) void*)(g),
        (__attribute__((address_space(3))) void*)(l), 16, 0, 0);
}

DEVI f32x4 mfma16(s16x8 a, s16x8 b, f32x4 c) {
    return __builtin_amdgcn_mfma_f32_16x16x32_bf16(
        __builtin_bit_cast(bf16x8, a), __builtin_bit_cast(bf16x8, b), c, 0, 0, 0);
}

// ---------------------------------------------------------------------------
// Tiled transpose + fp32->bf16: dst[n][k] = src[k][n].  64x64 tile, 256 thr.
// ---------------------------------------------------------------------------
__global__ __launch_bounds__(256) void transpose_cvt(
    const float* __restrict__ src, u16* __restrict__ dst,
    int K, int N, long srcStride, long dstStride)
{
    __shared__ float t[64][65];
    src += (long)blockIdx.z * srcStride;
    dst += (long)blockIdx.z * dstStride;
    int k0 = blockIdx.x * 64, n0 = blockIdx.y * 64;
    int tx = threadIdx.x & 63, ty = threadIdx.x >> 6;
#pragma unroll
    for (int i = 0; i < 16; ++i) {
        int r = ty * 16 + i;
        t[r][tx] = src[(long)(k0 + r) * N + n0 + tx];
    }
    __syncthreads();
#pragma unroll
    for (int i = 0; i < 16; ++i) {
        int r = ty * 16 + i;
        dst[(long)(n0 + r) * K + k0 + tx] = f2bf(t[tx][r]);
    }
}

// ---------------------------------------------------------------------------
// LayerNorm row (C=1024) -> bf16.  1 row / block, 256 threads, float4 loads.
// ---------------------------------------------------------------------------
__global__ __launch_bounds__(256) void ln_bf16(
    const float* __restrict__ x, const float* __restrict__ g,
    const float* __restrict__ b, u16* __restrict__ out)
{
    int row = blockIdx.x, tid = threadIdx.x;
    const float4 v = ((const float4*)(x + (long)row * 1024))[tid];
    float s = v.x + v.y + v.z + v.w;
    float q = v.x * v.x + v.y * v.y + v.z * v.z + v.w * v.w;
#pragma unroll
    for (int m = 1; m < 64; m <<= 1) { s += __shfl_xor(s, m); q += __shfl_xor(q, m); }
    __shared__ float red[8];
    int lane = tid & 63, w = tid >> 6;
    if (lane == 0) { red[w] = s; red[w + 4] = q; }
    __syncthreads();
    s = red[0] + red[1] + red[2] + red[3];
    q = red[4] + red[5] + red[6] + red[7];
    float mu  = s * (1.0f / 1024.0f);
    float var = q * (1.0f / 1024.0f) - mu * mu;
    float rs  = rsqrtf(var + 1e-5f);
    float4 gv = ((const float4*)g)[tid];
    float4 bv = ((const float4*)b)[tid];
    ushort4 o;
    o.x = f2bf((v.x - mu) * rs * gv.x + bv.x);
    o.y = f2bf((v.y - mu) * rs * gv.y + bv.y);
    o.z = f2bf((v.z - mu) * rs * gv.z + bv.z);
    o.w = f2bf((v.w - mu) * rs * gv.w + bv.w);
    ((ushort4*)(out + (long)row * 1024))[tid] = o;
}

// ---------------------------------------------------------------------------
// GEMM: C[M,N] = A[M,K] * B[K,N], A row-major bf16, Bt = B^T [N][K] bf16.
// 128x128 tile, BK=32, 4 waves (2x2), 4x4 16x16x32 MFMA frags per wave.
// m97 structure: global_load_lds(16B) staging, 2 barriers per K-step.
// EPI: 0 = QKV scatter, 1 = +bias +resid -> fp32, 2 = relu(+bias) -> bf16
// ---------------------------------------------------------------------------
template <int EPI>
__global__ __launch_bounds__(256, 3) void gemm_bt(
    const u16* __restrict__ A, const u16* __restrict__ Bt,
    int M, int N, int K,
    float* __restrict__ outF, u16* __restrict__ outB,
    const float* __restrict__ bias, const float* __restrict__ resid,
    u16* __restrict__ qd, u16* __restrict__ kd, u16* __restrict__ vd)
{
    __shared__ alignas(16) u16 As[128 * 32];
    __shared__ alignas(16) u16 Bs[128 * 32];
    int tid = threadIdx.x;
    int lane = tid & 63, w = tid >> 6;
    int wm = w & 1, wn = w >> 1;
    int l15 = lane & 15, l4 = lane >> 4;
    long m0 = (long)blockIdx.x * 128, n0 = (long)blockIdx.y * 128;
    const u16* Ag = A + m0 * K;
    const u16* Bg = Bt + n0 * K;
    int scol = (lane & 3) * 8;
    int srow0 = (w * 2 + 0) * 16 + (lane >> 2);
    int srow1 = (w * 2 + 1) * 16 + (lane >> 2);

    f32x4 acc[4][4] = {};

    for (int kt = 0; kt < K; kt += 32) {
        gload_lds16(Ag + (long)srow0 * K + kt + scol, &As[(w * 2 + 0) * 512]);
        gload_lds16(Ag + (long)srow1 * K + kt + scol, &As[(w * 2 + 1) * 512]);
        gload_lds16(Bg + (long)srow0 * K + kt + scol, &Bs[(w * 2 + 0) * 512]);
        gload_lds16(Bg + (long)srow1 * K + kt + scol, &Bs[(w * 2 + 1) * 512]);
        __syncthreads();
        s16x8 a[4], b[4];
#pragma unroll
        for (int m = 0; m < 4; ++m)
            a[m] = *(const s16x8*)&As[(wm * 64 + m * 16 + l15) * 32 + l4 * 8];
#pragma unroll
        for (int n = 0; n < 4; ++n)
            b[n] = *(const s16x8*)&Bs[(wn * 64 + n * 16 + l15) * 32 + l4 * 8];
#pragma unroll
        for (int m = 0; m < 4; ++m)
#pragma unroll
            for (int n = 0; n < 4; ++n)
                acc[m][n] = mfma16(a[m], b[n], acc[m][n]);
        __syncthreads();
    }

    long mbase = m0 + wm * 64;
    long nbase = n0 + wn * 64;
#pragma unroll
    for (int m = 0; m < 4; ++m)
#pragma unroll
        for (int n = 0; n < 4; ++n)
#pragma unroll
            for (int r = 0; r < 4; ++r) {
                long row = mbase + m * 16 + l4 * 4 + r;
                long col = nbase + n * 16 + l15;
                float val = acc[m][n][r];
                if constexpr (EPI == 0) {
                    int c = (int)col;
                    int which = c >> 10, hh = (c >> 6) & 15, dd = c & 63;
                    int bb = (int)(row >> 11), tt = (int)(row & 2047);
                    u16* dst = which == 0 ? qd : (which == 1 ? kd : vd);
                    dst[((long)(bb * 16 + hh) * 2048 + tt) * 64 + dd] = f2bf(val);
                } else if constexpr (EPI == 1) {
                    outF[row * N + col] = val + bias[col] + resid[row * N + col];
                } else {
                    float t2 = val + bias[col];
                    outB[row * N + col] = f2bf(t2 > 0.f ? t2 : 0.f);
                }
            }
}

// ---------------------------------------------------------------------------
// Causal flash attention.  Block = (b,h,qtile64), 4 waves x 16 q-rows.
// K/V tiles (64x64 bf16) staged in LDS with +8 pad (stride 144B: the
// ds_read_b128 B-frags then hit <=2 lanes/bank = free).  Softmax fully
// wave-parallel via 16-lane shfl_xor reductions.  P transposed via per-wave
// LDS region to feed the PV MFMA A-operand.
// ---------------------------------------------------------------------------
__global__ __launch_bounds__(256, 2) void attn_kernel(
    const u16* __restrict__ Q, const u16* __restrict__ K,
    const u16* __restrict__ V, u16* __restrict__ O)
{
    constexpr int PAD = 72;
    __shared__ alignas(16) u16 Ks[64 * PAD];
    __shared__ alignas(16) u16 Vs[64 * PAD];
    __shared__ alignas(16) u16 Ps[4 * 16 * PAD];
    int tid = threadIdx.x, lane = tid & 63, w = tid >> 6;
    int l15 = lane & 15, l4 = lane >> 4;
    int qt = blockIdx.x, hh = blockIdx.y, bb = blockIdx.z;
    const long hbase = ((long)(bb * 16 + hh)) * 2048 * 64;
    int q0 = qt * 64 + w * 16;

    s16x8 aq[2];
#pragma unroll
    for (int kk = 0; kk < 2; ++kk)
        aq[kk] = *(const s16x8*)&Q[hbase + (long)(q0 + l15) * 64 + kk * 32 + l4 * 8];

    f32x4 o[4] = {};
    float mrow[4] = {-1e30f, -1e30f, -1e30f, -1e30f};
    float lrow[4] = {0.f, 0.f, 0.f, 0.f};
    u16* pw = &Ps[w * 16 * PAD];

    for (int kt = 0; kt <= qt; ++kt) {
        const u16* Kg = K + hbase + (long)kt * 64 * 64;
        const u16* Vg = V + hbase + (long)kt * 64 * 64;
#pragma unroll
        for (int c = 0; c < 2; ++c) {
            int chunk = tid + 256 * c;
            int row = chunk >> 3, cc = chunk & 7;
            *(s16x8*)&Ks[row * PAD + cc * 8] = *(const s16x8*)&Kg[row * 64 + cc * 8];
            *(s16x8*)&Vs[row * PAD + cc * 8] = *(const s16x8*)&Vg[row * 64 + cc * 8];
        }
        __syncthreads();

        // S = Q K^T  (16 x 64 per wave)
        f32x4 s[4];
#pragma unroll
        for (int n = 0; n < 4; ++n) {
            s16x8 bk0 = *(const s16x8*)&Ks[(n * 16 + l15) * PAD + l4 * 8];
            s16x8 bk1 = *(const s16x8*)&Ks[(n * 16 + l15) * PAD + 32 + l4 * 8];
            f32x4 z = {0.f, 0.f, 0.f, 0.f};
            z = mfma16(aq[0], bk0, z);
            z = mfma16(aq[1], bk1, z);
            s[n] = z;
        }

        // scale + causal mask (only diagonal tile)
        float pm[4] = {-1e30f, -1e30f, -1e30f, -1e30f};
        bool diag = (kt == qt);
#pragma unroll
        for (int n = 0; n < 4; ++n)
#pragma unroll
            for (int r = 0; r < 4; ++r) {
                float sv = s[n][r] * 0.125f;
                if (diag) {
                    int kloc = n * 16 + l15;
                    int qloc = w * 16 + l4 * 4 + r;
                    if (kloc > qloc) sv = -1e30f;
                }
                s[n][r] = sv;
                pm[r] = fmaxf(pm[r], sv);
            }
#pragma unroll
        for (int xm = 1; xm < 16; xm <<= 1)
#pragma unroll
            for (int r = 0; r < 4; ++r) pm[r] = fmaxf(pm[r], __shfl_xor(pm[r], xm));

        float ef[4], rsum[4] = {0.f, 0.f, 0.f, 0.f};
#pragma unroll
        for (int r = 0; r < 4; ++r) {
            float mn = fmaxf(mrow[r], pm[r]);
            ef[r] = __expf(mrow[r] - mn);
            mrow[r] = mn;
        }
#pragma unroll
        for (int n = 0; n < 4; ++n)
#pragma unroll
            for (int r = 0; r < 4; ++r) {
                float p = __expf(s[n][r] - mrow[r]);
                s[n][r] = p;
                rsum[r] += p;
            }
#pragma unroll
        for (int xm = 1; xm < 16; xm <<= 1)
#pragma unroll
            for (int r = 0; r < 4; ++r) rsum[r] += __shfl_xor(rsum[r], xm);
#pragma unroll
        for (int r = 0; r < 4; ++r) lrow[r] = lrow[r] * ef[r] + rsum[r];
#pragma unroll
        for (int n = 0; n < 4; ++n)
#pragma unroll
            for (int r = 0; r < 4; ++r) o[n][r] *= ef[r];

        // P (D-layout) -> per-wave LDS -> A-frag layout
#pragma unroll
        for (int n = 0; n < 4; ++n)
#pragma unroll
            for (int r = 0; r < 4; ++r)
                pw[(l4 * 4 + r) * PAD + n * 16 + l15] = f2bf(s[n][r]);

        s16x8 pa0 = *(const s16x8*)&pw[l15 * PAD + l4 * 8];
        s16x8 pa1 = *(const s16x8*)&pw[l15 * PAD + 32 + l4 * 8];
#pragma unroll
        for (int n = 0; n < 4; ++n) {
            s16x8 bv0, bv1;
#pragma unroll
            for (int j = 0; j < 8; ++j) {
                bv0[j] = (short)Vs[(l4 * 8 + j) * PAD + n * 16 + l15];
                bv1[j] = (short)Vs[(32 + l4 * 8 + j) * PAD + n * 16 + l15];
            }
            o[n] = mfma16(pa0, bv0, o[n]);
            o[n] = mfma16(pa1, bv1, o[n]);
        }
        __syncthreads();
    }

    float invl[4];
#pragma unroll
    for (int r = 0; r < 4; ++r) invl[r] = 1.0f / lrow[r];
#pragma unroll
    for (int n = 0; n < 4; ++n)
#pragma unroll
        for (int r = 0; r < 4; ++r) {
            int t = qt * 64 + w * 16 + l4 * 4 + r;
            O[((long)(bb * 2048 + t)) * 1024 + hh * 64 + n * 16 + l15] =
                f2bf(o[n][r] * invl[r]);
        }
}

// ---------------------------------------------------------------------------
extern "C" void kernel_launch(void* const* d_in, const int* in_sizes, int n_in,
                              void* d_out, int out_size, void* d_ws, size_t ws_size,
                              hipStream_t stream)
{
    const float* x      = (const float*)d_in[0];
    const float* wq     = (const float*)d_in[1];
    const float* wk     = (const float*)d_in[2];
    const float* wv     = (const float*)d_in[3];
    const float* w_proj = (const float*)d_in[4];
    const float* b_proj = (const float*)d_in[5];
    const float* w1     = (const float*)d_in[6];
    const float* b1     = (const float*)d_in[7];
    const float* w2     = (const float*)d_in[8];
    const float* b2     = (const float*)d_in[9];
    const float* ln1_g  = (const float*)d_in[10];
    const float* ln1_b  = (const float*)d_in[11];
    const float* ln2_g  = (const float*)d_in[12];
    const float* ln2_b  = (const float*)d_in[13];

    char* ws = (char*)d_ws;
    // ws layout (bytes); FF overlaps dead Q/K/V/O. Total 142,606,336 B.
    u16*   WQKVt = (u16*)(ws + 0);           // 3072x1024 bf16  (6.29 MB)
    u16*   WPt   = (u16*)(ws + 6291456);     // 1024x1024       (2.10 MB)
    u16*   W1t   = (u16*)(ws + 8388608);     // 4096x1024       (8.39 MB)
    u16*   W2t   = (u16*)(ws + 16777216);    // 1024x4096       (8.39 MB)
    u16*   H     = (u16*)(ws + 25165824);    // 8192x1024 (h, then h2)
    u16*   Qb    = (u16*)(ws + 41943040);    // [B,H,T,D]
    u16*   Kb    = (u16*)(ws + 58720256);
    u16*   Vb    = (u16*)(ws + 75497472);
    u16*   Ob    = (u16*)(ws + 92274688);    // [B,T,C]
    u16*   FF    = (u16*)(ws + 41943040);    // 8192x4096, overlaps Q..O
    float* X1    = (float*)(ws + 109051904); // 8192x1024 fp32
    float* out   = (float*)d_out;

    // weights -> bf16 B^T
    transpose_cvt<<<dim3(16, 1, 16), 256, 0, stream>>>(wq, WQKVt,           1024, 64, 65536, 65536);
    transpose_cvt<<<dim3(16, 1, 16), 256, 0, stream>>>(wk, WQKVt + 1048576, 1024, 64, 65536, 65536);
    transpose_cvt<<<dim3(16, 1, 16), 256, 0, stream>>>(wv, WQKVt + 2097152, 1024, 64, 65536, 65536);
    transpose_cvt<<<dim3(16, 16, 1), 256, 0, stream>>>(w_proj, WPt, 1024, 1024, 0, 0);
    transpose_cvt<<<dim3(16, 64, 1), 256, 0, stream>>>(w1, W1t, 1024, 4096, 0, 0);
    transpose_cvt<<<dim3(64, 16, 1), 256, 0, stream>>>(w2, W2t, 4096, 1024, 0, 0);

    ln_bf16<<<8192, 256, 0, stream>>>(x, ln1_g, ln1_b, H);

    gemm_bt<0><<<dim3(64, 24), 256, 0, stream>>>(H, WQKVt, 8192, 3072, 1024,
        nullptr, nullptr, nullptr, nullptr, Qb, Kb, Vb);

    attn_kernel<<<dim3(32, 16, 4), 256, 0, stream>>>(Qb, Kb, Vb, Ob);

    gemm_bt<1><<<dim3(64, 8), 256, 0, stream>>>(Ob, WPt, 8192, 1024, 1024,
        X1, nullptr, b_proj, x, nullptr, nullptr, nullptr);

    ln_bf16<<<8192, 256, 0, stream>>>(X1, ln2_g, ln2_b, H);

    gemm_bt<2><<<dim3(64, 32), 256, 0, stream>>>(H, W1t, 8192, 4096, 1024,
        nullptr, FF, b1, nullptr, nullptr, nullptr, nullptr);

    gemm_bt<1><<<dim3(64, 8), 256, 0, stream>>>(FF, W2t, 8192, 1024, 4096,
        out, nullptr, b2, X1, nullptr, nullptr, nullptr);
}

// Round 2
// 560.135 us; speedup vs baseline: 1.0670x; 1.0670x over previous
//
#include <hip/hip_runtime.h>

// ---------------------------------------------------------------------------
// TransformerBlock on MI355X (gfx950), bf16 MFMA internal compute.
// B=4 T=2048 C=1024 H=16 D=64 FF=4096. All fp32 I/O; bf16 internally.
//
// R1: attention rewrite. V stored transposed [B,H,D,T] (free, in QKV-GEMM
// epilogue) so PV B-frags are contiguous ds_read_b128; 128 q-rows/block
// (4 waves x 32 rows); all fragment reads vectorized. Kills the 64 scalar
// ds_read_u16/lane/tile + 2.3e7 bank conflicts of R0.
// ---------------------------------------------------------------------------

#define DEVI __device__ __forceinline__

typedef float  f32x4  __attribute__((ext_vector_type(4)));
typedef __bf16 bf16x8 __attribute__((ext_vector_type(8)));
typedef short  s16x8  __attribute__((ext_vector_type(8)));
typedef unsigned short u16;

DEVI u16 f2bf(float f) {            // RNE fp32 -> bf16 bits
    unsigned u = __builtin_bit_cast(unsigned, f);
    u += 0x7fffu + ((u >> 16) & 1u);
    return (u16)(u >> 16);
}

DEVI void gload_lds16(const void* g, void* l) {
    __builtin_amdgcn_global_load_lds(
        (__attribute__((address_space(1))) void*)(g),
        (__attribute__((address_space(3))) void*)(l), 16, 0, 0);
}

DEVI f32x4 mfma16(s16x8 a, s16x8 b, f32x4 c) {
    return __builtin_amdgcn_mfma_f32_16x16x32_bf16(
        __builtin_bit_cast(bf16x8, a), __builtin_bit_cast(bf16x8, b), c, 0, 0, 0);
}

// ---------------------------------------------------------------------------
// Tiled transpose + fp32->bf16: dst[n][k] = src[k][n].  64x64 tile, 256 thr.
// ---------------------------------------------------------------------------
__global__ __launch_bounds__(256) void transpose_cvt(
    const float* __restrict__ src, u16* __restrict__ dst,
    int K, int N, long srcStride, long dstStride)
{
    __shared__ float t[64][65];
    src += (long)blockIdx.z * srcStride;
    dst += (long)blockIdx.z * dstStride;
    int k0 = blockIdx.x * 64, n0 = blockIdx.y * 64;
    int tx = threadIdx.x & 63, ty = threadIdx.x >> 6;
#pragma unroll
    for (int i = 0; i < 16; ++i) {
        int r = ty * 16 + i;
        t[r][tx] = src[(long)(k0 + r) * N + n0 + tx];
    }
    __syncthreads();
#pragma unroll
    for (int i = 0; i < 16; ++i) {
        int r = ty * 16 + i;
        dst[(long)(n0 + r) * K + k0 + tx] = f2bf(t[tx][r]);
    }
}

// ---------------------------------------------------------------------------
// LayerNorm row (C=1024) -> bf16.  1 row / block, 256 threads, float4 loads.
// ---------------------------------------------------------------------------
__global__ __launch_bounds__(256) void ln_bf16(
    const float* __restrict__ x, const float* __restrict__ g,
    const float* __restrict__ b, u16* __restrict__ out)
{
    int row = blockIdx.x, tid = threadIdx.x;
    const float4 v = ((const float4*)(x + (long)row * 1024))[tid];
    float s = v.x + v.y + v.z + v.w;
    float q = v.x * v.x + v.y * v.y + v.z * v.z + v.w * v.w;
#pragma unroll
    for (int m = 1; m < 64; m <<= 1) { s += __shfl_xor(s, m); q += __shfl_xor(q, m); }
    __shared__ float red[8];
    int lane = tid & 63, w = tid >> 6;
    if (lane == 0) { red[w] = s; red[w + 4] = q; }
    __syncthreads();
    s = red[0] + red[1] + red[2] + red[3];
    q = red[4] + red[5] + red[6] + red[7];
    float mu  = s * (1.0f / 1024.0f);
    float var = q * (1.0f / 1024.0f) - mu * mu;
    float rs  = rsqrtf(var + 1e-5f);
    float4 gv = ((const float4*)g)[tid];
    float4 bv = ((const float4*)b)[tid];
    ushort4 o;
    o.x = f2bf((v.x - mu) * rs * gv.x + bv.x);
    o.y = f2bf((v.y - mu) * rs * gv.y + bv.y);
    o.z = f2bf((v.z - mu) * rs * gv.z + bv.z);
    o.w = f2bf((v.w - mu) * rs * gv.w + bv.w);
    ((ushort4*)(out + (long)row * 1024))[tid] = o;
}

// ---------------------------------------------------------------------------
// GEMM: C[M,N] = A[M,K] * B[K,N], A row-major bf16, Bt = B^T [N][K] bf16.
// 128x128 tile, BK=32, 4 waves (2x2), 4x4 16x16x32 MFMA frags per wave.
// EPI: 0 = QKV scatter (V transposed!), 1 = +bias +resid -> fp32,
//      2 = relu(+bias) -> bf16
// ---------------------------------------------------------------------------
template <int EPI>
__global__ __launch_bounds__(256, 3) void gemm_bt(
    const u16* __restrict__ A, const u16* __restrict__ Bt,
    int M, int N, int K,
    float* __restrict__ outF, u16* __restrict__ outB,
    const float* __restrict__ bias, const float* __restrict__ resid,
    u16* __restrict__ qd, u16* __restrict__ kd, u16* __restrict__ vd)
{
    __shared__ alignas(16) u16 As[128 * 32];
    __shared__ alignas(16) u16 Bs[128 * 32];
    int tid = threadIdx.x;
    int lane = tid & 63, w = tid >> 6;
    int wm = w & 1, wn = w >> 1;
    int l15 = lane & 15, l4 = lane >> 4;
    long m0 = (long)blockIdx.x * 128, n0 = (long)blockIdx.y * 128;
    const u16* Ag = A + m0 * K;
    const u16* Bg = Bt + n0 * K;
    int scol = (lane & 3) * 8;
    int srow0 = (w * 2 + 0) * 16 + (lane >> 2);
    int srow1 = (w * 2 + 1) * 16 + (lane >> 2);

    f32x4 acc[4][4] = {};

    for (int kt = 0; kt < K; kt += 32) {
        gload_lds16(Ag + (long)srow0 * K + kt + scol, &As[(w * 2 + 0) * 512]);
        gload_lds16(Ag + (long)srow1 * K + kt + scol, &As[(w * 2 + 1) * 512]);
        gload_lds16(Bg + (long)srow0 * K + kt + scol, &Bs[(w * 2 + 0) * 512]);
        gload_lds16(Bg + (long)srow1 * K + kt + scol, &Bs[(w * 2 + 1) * 512]);
        __syncthreads();
        s16x8 a[4], b[4];
#pragma unroll
        for (int m = 0; m < 4; ++m)
            a[m] = *(const s16x8*)&As[(wm * 64 + m * 16 + l15) * 32 + l4 * 8];
#pragma unroll
        for (int n = 0; n < 4; ++n)
            b[n] = *(const s16x8*)&Bs[(wn * 64 + n * 16 + l15) * 32 + l4 * 8];
#pragma unroll
        for (int m = 0; m < 4; ++m)
#pragma unroll
            for (int n = 0; n < 4; ++n)
                acc[m][n] = mfma16(a[m], b[n], acc[m][n]);
        __syncthreads();
    }

    long mbase = m0 + wm * 64;
    long nbase = n0 + wn * 64;
#pragma unroll
    for (int m = 0; m < 4; ++m)
#pragma unroll
        for (int n = 0; n < 4; ++n)
#pragma unroll
            for (int r = 0; r < 4; ++r) {
                long row = mbase + m * 16 + l4 * 4 + r;
                long col = nbase + n * 16 + l15;
                float val = acc[m][n][r];
                if constexpr (EPI == 0) {
                    int c = (int)col;
                    int which = c >> 10, hh = (c >> 6) & 15, dd = c & 63;
                    int bb = (int)(row >> 11), tt = (int)(row & 2047);
                    if (which == 2) {
                        // V transposed: [B,H,D,T]
                        vd[((long)(bb * 16 + hh) * 64 + dd) * 2048 + tt] = f2bf(val);
                    } else {
                        u16* dst = which == 0 ? qd : kd;
                        dst[((long)(bb * 16 + hh) * 2048 + tt) * 64 + dd] = f2bf(val);
                    }
                } else if constexpr (EPI == 1) {
                    outF[row * N + col] = val + bias[col] + resid[row * N + col];
                } else {
                    float t2 = val + bias[col];
                    outB[row * N + col] = f2bf(t2 > 0.f ? t2 : 0.f);
                }
            }
}

// ---------------------------------------------------------------------------
// Causal flash attention.  Block = (b,h,qtile128), 4 waves x 32 q-rows.
// K staged [s][d] and V staged transposed [d][s] in LDS (PAD=72 keeps
// ds_read_b128 16B-aligned and bank-balanced).  All MFMA fragment reads are
// ds_read_b128.  Softmax wave-parallel via 16-lane shfl_xor.
// ---------------------------------------------------------------------------
__global__ __launch_bounds__(256, 3) void attn_kernel(
    const u16* __restrict__ Q, const u16* __restrict__ K,
    const u16* __restrict__ Vt, u16* __restrict__ O)
{
    constexpr int PAD = 72;
    __shared__ alignas(16) u16 Ks[64 * PAD];
    __shared__ alignas(16) u16 Vts[64 * PAD];
    __shared__ alignas(16) u16 Ps[4 * 32 * PAD];
    int tid = threadIdx.x, lane = tid & 63, w = tid >> 6;
    int l15 = lane & 15, l4 = lane >> 4;
    int qt = blockIdx.x, hh = blockIdx.y, bb = blockIdx.z;
    const long hbase = ((long)(bb * 16 + hh)) * 2048 * 64;
    int q0w = qt * 128 + w * 32;           // this wave's first q row

    // Q fragments: 2 m-frags x 2 k-chunks
    s16x8 aq[2][2];
#pragma unroll
    for (int m = 0; m < 2; ++m)
#pragma unroll
        for (int kk = 0; kk < 2; ++kk)
            aq[m][kk] = *(const s16x8*)&Q[hbase + (long)(q0w + m * 16 + l15) * 64 + kk * 32 + l4 * 8];

    f32x4 o[2][4] = {};
    float mrow[2][4], lrow[2][4];
#pragma unroll
    for (int m = 0; m < 2; ++m)
#pragma unroll
        for (int r = 0; r < 4; ++r) { mrow[m][r] = -1e30f; lrow[m][r] = 0.f; }
    u16* pw = &Ps[w * 32 * PAD];

    int nt = 2 * qt + 2;                   // k-tiles needed (64 wide)
    for (int kt = 0; kt < nt; ++kt) {
        const u16* Kg = K + hbase + (long)kt * 64 * 64;      // [s][d]
        const u16* Vg = Vt + hbase + (long)kt * 64;          // [d][t], row stride 2048
#pragma unroll
        for (int c = 0; c < 2; ++c) {
            int chunk = tid + 256 * c;
            int row = chunk >> 3, cc = chunk & 7;
            *(s16x8*)&Ks[row * PAD + cc * 8]  = *(const s16x8*)&Kg[row * 64 + cc * 8];
            *(s16x8*)&Vts[row * PAD + cc * 8] = *(const s16x8*)&Vg[(long)row * 2048 + cc * 8];
        }
        __syncthreads();

        // K fragments (shared across both m-frags)
        s16x8 bk[4][2];
#pragma unroll
        for (int n = 0; n < 4; ++n)
#pragma unroll
            for (int kk = 0; kk < 2; ++kk)
                bk[n][kk] = *(const s16x8*)&Ks[(n * 16 + l15) * PAD + kk * 32 + l4 * 8];

        bool needMask = (kt * 64 + 63 > q0w);
#pragma unroll
        for (int m = 0; m < 2; ++m) {
            f32x4 s[4];
#pragma unroll
            for (int n = 0; n < 4; ++n) {
                f32x4 z = {0.f, 0.f, 0.f, 0.f};
                z = mfma16(aq[m][0], bk[n][0], z);
                z = mfma16(aq[m][1], bk[n][1], z);
                s[n] = z;
            }
            float pm[4] = {-1e30f, -1e30f, -1e30f, -1e30f};
#pragma unroll
            for (int n = 0; n < 4; ++n)
#pragma unroll
                for (int r = 0; r < 4; ++r) {
                    float sv = s[n][r] * 0.125f;
                    if (needMask) {
                        int kglob = kt * 64 + n * 16 + l15;
                        int qglob = q0w + m * 16 + l4 * 4 + r;
                        if (kglob > qglob) sv = -1e30f;
                    }
                    s[n][r] = sv;
                    pm[r] = fmaxf(pm[r], sv);
                }
#pragma unroll
            for (int xm = 1; xm < 16; xm <<= 1)
#pragma unroll
                for (int r = 0; r < 4; ++r) pm[r] = fmaxf(pm[r], __shfl_xor(pm[r], xm));

            float ef[4], rsum[4] = {0.f, 0.f, 0.f, 0.f};
#pragma unroll
            for (int r = 0; r < 4; ++r) {
                float mn = fmaxf(mrow[m][r], pm[r]);
                ef[r] = __expf(mrow[m][r] - mn);
                mrow[m][r] = mn;
            }
#pragma unroll
            for (int n = 0; n < 4; ++n)
#pragma unroll
                for (int r = 0; r < 4; ++r) {
                    float p = __expf(s[n][r] - mrow[m][r]);
                    s[n][r] = p;
                    rsum[r] += p;
                }
#pragma unroll
            for (int xm = 1; xm < 16; xm <<= 1)
#pragma unroll
                for (int r = 0; r < 4; ++r) rsum[r] += __shfl_xor(rsum[r], xm);
#pragma unroll
            for (int r = 0; r < 4; ++r) lrow[m][r] = lrow[m][r] * ef[r] + rsum[r];
#pragma unroll
            for (int n = 0; n < 4; ++n)
#pragma unroll
                for (int r = 0; r < 4; ++r) o[m][n][r] *= ef[r];

            // P (C-layout) -> per-wave LDS (rows = local q, cols = s)
#pragma unroll
            for (int n = 0; n < 4; ++n)
#pragma unroll
                for (int r = 0; r < 4; ++r)
                    pw[(m * 16 + l4 * 4 + r) * PAD + n * 16 + l15] = f2bf(s[n][r]);
        }

        // PV: pa = P A-frags, bv = V^T B-frags, all ds_read_b128
        s16x8 pa[2][2], bv[4][2];
#pragma unroll
        for (int m = 0; m < 2; ++m)
#pragma unroll
            for (int kk = 0; kk < 2; ++kk)
                pa[m][kk] = *(const s16x8*)&pw[(m * 16 + l15) * PAD + kk * 32 + l4 * 8];
#pragma unroll
        for (int n = 0; n < 4; ++n)
#pragma unroll
            for (int kk = 0; kk < 2; ++kk)
                bv[n][kk] = *(const s16x8*)&Vts[(n * 16 + l15) * PAD + kk * 32 + l4 * 8];
#pragma unroll
        for (int m = 0; m < 2; ++m)
#pragma unroll
            for (int n = 0; n < 4; ++n) {
                o[m][n] = mfma16(pa[m][0], bv[n][0], o[m][n]);
                o[m][n] = mfma16(pa[m][1], bv[n][1], o[m][n]);
            }
        __syncthreads();
    }

#pragma unroll
    for (int m = 0; m < 2; ++m) {
        float invl[4];
#pragma unroll
        for (int r = 0; r < 4; ++r) invl[r] = 1.0f / lrow[m][r];
#pragma unroll
        for (int n = 0; n < 4; ++n)
#pragma unroll
            for (int r = 0; r < 4; ++r) {
                int t = q0w + m * 16 + l4 * 4 + r;
                O[((long)(bb * 2048 + t)) * 1024 + hh * 64 + n * 16 + l15] =
                    f2bf(o[m][n][r] * invl[r]);
            }
    }
}

// ---------------------------------------------------------------------------
extern "C" void kernel_launch(void* const* d_in, const int* in_sizes, int n_in,
                              void* d_out, int out_size, void* d_ws, size_t ws_size,
                              hipStream_t stream)
{
    const float* x      = (const float*)d_in[0];
    const float* wq     = (const float*)d_in[1];
    const float* wk     = (const float*)d_in[2];
    const float* wv     = (const float*)d_in[3];
    const float* w_proj = (const float*)d_in[4];
    const float* b_proj = (const float*)d_in[5];
    const float* w1     = (const float*)d_in[6];
    const float* b1     = (const float*)d_in[7];
    const float* w2     = (const float*)d_in[8];
    const float* b2     = (const float*)d_in[9];
    const float* ln1_g  = (const float*)d_in[10];
    const float* ln1_b  = (const float*)d_in[11];
    const float* ln2_g  = (const float*)d_in[12];
    const float* ln2_b  = (const float*)d_in[13];

    char* ws = (char*)d_ws;
    u16*   WQKVt = (u16*)(ws + 0);           // 3072x1024 bf16
    u16*   WPt   = (u16*)(ws + 6291456);     // 1024x1024
    u16*   W1t   = (u16*)(ws + 8388608);     // 4096x1024
    u16*   W2t   = (u16*)(ws + 16777216);    // 1024x4096
    u16*   H     = (u16*)(ws + 25165824);    // 8192x1024 (h, then h2)
    u16*   Qb    = (u16*)(ws + 41943040);    // [B,H,T,D]
    u16*   Kb    = (u16*)(ws + 58720256);    // [B,H,T,D]
    u16*   Vb    = (u16*)(ws + 75497472);    // [B,H,D,T]  (transposed)
    u16*   Ob    = (u16*)(ws + 92274688);    // [B,T,C]
    u16*   FF    = (u16*)(ws + 41943040);    // 8192x4096, overlaps Q..O
    float* X1    = (float*)(ws + 109051904); // 8192x1024 fp32
    float* out   = (float*)d_out;

    transpose_cvt<<<dim3(16, 1, 16), 256, 0, stream>>>(wq, WQKVt,           1024, 64, 65536, 65536);
    transpose_cvt<<<dim3(16, 1, 16), 256, 0, stream>>>(wk, WQKVt + 1048576, 1024, 64, 65536, 65536);
    transpose_cvt<<<dim3(16, 1, 16), 256, 0, stream>>>(wv, WQKVt + 2097152, 1024, 64, 65536, 65536);
    transpose_cvt<<<dim3(16, 16, 1), 256, 0, stream>>>(w_proj, WPt, 1024, 1024, 0, 0);
    transpose_cvt<<<dim3(16, 64, 1), 256, 0, stream>>>(w1, W1t, 1024, 4096, 0, 0);
    transpose_cvt<<<dim3(64, 16, 1), 256, 0, stream>>>(w2, W2t, 4096, 1024, 0, 0);

    ln_bf16<<<8192, 256, 0, stream>>>(x, ln1_g, ln1_b, H);

    gemm_bt<0><<<dim3(64, 24), 256, 0, stream>>>(H, WQKVt, 8192, 3072, 1024,
        nullptr, nullptr, nullptr, nullptr, Qb, Kb, Vb);

    attn_kernel<<<dim3(16, 16, 4), 256, 0, stream>>>(Qb, Kb, Vb, Ob);

    gemm_bt<1><<<dim3(64, 8), 256, 0, stream>>>(Ob, WPt, 8192, 1024, 1024,
        X1, nullptr, b_proj, x, nullptr, nullptr, nullptr);

    ln_bf16<<<8192, 256, 0, stream>>>(X1, ln2_g, ln2_b, H);

    gemm_bt<2><<<dim3(64, 32), 256, 0, stream>>>(H, W1t, 8192, 4096, 1024,
        nullptr, FF, b1, nullptr, nullptr, nullptr, nullptr);

    gemm_bt<1><<<dim3(64, 8), 256, 0, stream>>>(FF, W2t, 8192, 1024, 4096,
        out, nullptr, b2, X1, nullptr, nullptr, nullptr);
}

// Round 3
// 464.229 us; speedup vs baseline: 1.2875x; 1.2066x over previous
//
#include <hip/hip_runtime.h>

// ---------------------------------------------------------------------------
// TransformerBlock on MI355X (gfx950), bf16 MFMA internal compute.
// B=4 T=2048 C=1024 H=16 D=64 FF=4096. All fp32 I/O; bf16 internally.
//
// R2: attention restructure.
//  - balanced q-tile pairing: block p handles q-tiles {p, 15-p} (34 k-tiles
//    each, uniform) -> no load-imbalance tail.
//  - double-buffered K/V LDS with T14 async reg-staging (loads for tile t+2
//    issued before compute(t)); ONE barrier per k-tile.
//  - softmax in exp2 domain (scale folded), setprio around MFMA clusters.
// ---------------------------------------------------------------------------

#define DEVI __device__ __forceinline__

typedef float  f32x4  __attribute__((ext_vector_type(4)));
typedef __bf16 bf16x8 __attribute__((ext_vector_type(8)));
typedef short  s16x8  __attribute__((ext_vector_type(8)));
typedef unsigned short u16;

DEVI u16 f2bf(float f) {            // RNE fp32 -> bf16 bits
    unsigned u = __builtin_bit_cast(unsigned, f);
    u += 0x7fffu + ((u >> 16) & 1u);
    return (u16)(u >> 16);
}

DEVI void gload_lds16(const void* g, void* l) {
    __builtin_amdgcn_global_load_lds(
        (__attribute__((address_space(1))) void*)(g),
        (__attribute__((address_space(3))) void*)(l), 16, 0, 0);
}

DEVI f32x4 mfma16(s16x8 a, s16x8 b, f32x4 c) {
    return __builtin_amdgcn_mfma_f32_16x16x32_bf16(
        __builtin_bit_cast(bf16x8, a), __builtin_bit_cast(bf16x8, b), c, 0, 0, 0);
}

// ---------------------------------------------------------------------------
// Tiled transpose + fp32->bf16: dst[n][k] = src[k][n].  64x64 tile, 256 thr.
// ---------------------------------------------------------------------------
__global__ __launch_bounds__(256) void transpose_cvt(
    const float* __restrict__ src, u16* __restrict__ dst,
    int K, int N, long srcStride, long dstStride)
{
    __shared__ float t[64][65];
    src += (long)blockIdx.z * srcStride;
    dst += (long)blockIdx.z * dstStride;
    int k0 = blockIdx.x * 64, n0 = blockIdx.y * 64;
    int tx = threadIdx.x & 63, ty = threadIdx.x >> 6;
#pragma unroll
    for (int i = 0; i < 16; ++i) {
        int r = ty * 16 + i;
        t[r][tx] = src[(long)(k0 + r) * N + n0 + tx];
    }
    __syncthreads();
#pragma unroll
    for (int i = 0; i < 16; ++i) {
        int r = ty * 16 + i;
        dst[(long)(n0 + r) * K + k0 + tx] = f2bf(t[tx][r]);
    }
}

// ---------------------------------------------------------------------------
// LayerNorm row (C=1024) -> bf16.  1 row / block, 256 threads, float4 loads.
// ---------------------------------------------------------------------------
__global__ __launch_bounds__(256) void ln_bf16(
    const float* __restrict__ x, const float* __restrict__ g,
    const float* __restrict__ b, u16* __restrict__ out)
{
    int row = blockIdx.x, tid = threadIdx.x;
    const float4 v = ((const float4*)(x + (long)row * 1024))[tid];
    float s = v.x + v.y + v.z + v.w;
    float q = v.x * v.x + v.y * v.y + v.z * v.z + v.w * v.w;
#pragma unroll
    for (int m = 1; m < 64; m <<= 1) { s += __shfl_xor(s, m); q += __shfl_xor(q, m); }
    __shared__ float red[8];
    int lane = tid & 63, w = tid >> 6;
    if (lane == 0) { red[w] = s; red[w + 4] = q; }
    __syncthreads();
    s = red[0] + red[1] + red[2] + red[3];
    q = red[4] + red[5] + red[6] + red[7];
    float mu  = s * (1.0f / 1024.0f);
    float var = q * (1.0f / 1024.0f) - mu * mu;
    float rs  = rsqrtf(var + 1e-5f);
    float4 gv = ((const float4*)g)[tid];
    float4 bv = ((const float4*)b)[tid];
    ushort4 o;
    o.x = f2bf((v.x - mu) * rs * gv.x + bv.x);
    o.y = f2bf((v.y - mu) * rs * gv.y + bv.y);
    o.z = f2bf((v.z - mu) * rs * gv.z + bv.z);
    o.w = f2bf((v.w - mu) * rs * gv.w + bv.w);
    ((ushort4*)(out + (long)row * 1024))[tid] = o;
}

// ---------------------------------------------------------------------------
// GEMM: C[M,N] = A[M,K] * B[K,N], A row-major bf16, Bt = B^T [N][K] bf16.
// 128x128 tile, BK=32, 4 waves (2x2), 4x4 16x16x32 MFMA frags per wave.
// EPI: 0 = QKV scatter (V transposed!), 1 = +bias +resid -> fp32,
//      2 = relu(+bias) -> bf16
// ---------------------------------------------------------------------------
template <int EPI>
__global__ __launch_bounds__(256, 3) void gemm_bt(
    const u16* __restrict__ A, const u16* __restrict__ Bt,
    int M, int N, int K,
    float* __restrict__ outF, u16* __restrict__ outB,
    const float* __restrict__ bias, const float* __restrict__ resid,
    u16* __restrict__ qd, u16* __restrict__ kd, u16* __restrict__ vd)
{
    __shared__ alignas(16) u16 As[128 * 32];
    __shared__ alignas(16) u16 Bs[128 * 32];
    int tid = threadIdx.x;
    int lane = tid & 63, w = tid >> 6;
    int wm = w & 1, wn = w >> 1;
    int l15 = lane & 15, l4 = lane >> 4;
    long m0 = (long)blockIdx.x * 128, n0 = (long)blockIdx.y * 128;
    const u16* Ag = A + m0 * K;
    const u16* Bg = Bt + n0 * K;
    int scol = (lane & 3) * 8;
    int srow0 = (w * 2 + 0) * 16 + (lane >> 2);
    int srow1 = (w * 2 + 1) * 16 + (lane >> 2);

    f32x4 acc[4][4] = {};

    for (int kt = 0; kt < K; kt += 32) {
        gload_lds16(Ag + (long)srow0 * K + kt + scol, &As[(w * 2 + 0) * 512]);
        gload_lds16(Ag + (long)srow1 * K + kt + scol, &As[(w * 2 + 1) * 512]);
        gload_lds16(Bg + (long)srow0 * K + kt + scol, &Bs[(w * 2 + 0) * 512]);
        gload_lds16(Bg + (long)srow1 * K + kt + scol, &Bs[(w * 2 + 1) * 512]);
        __syncthreads();
        s16x8 a[4], b[4];
#pragma unroll
        for (int m = 0; m < 4; ++m)
            a[m] = *(const s16x8*)&As[(wm * 64 + m * 16 + l15) * 32 + l4 * 8];
#pragma unroll
        for (int n = 0; n < 4; ++n)
            b[n] = *(const s16x8*)&Bs[(wn * 64 + n * 16 + l15) * 32 + l4 * 8];
#pragma unroll
        for (int m = 0; m < 4; ++m)
#pragma unroll
            for (int n = 0; n < 4; ++n)
                acc[m][n] = mfma16(a[m], b[n], acc[m][n]);
        __syncthreads();
    }

    long mbase = m0 + wm * 64;
    long nbase = n0 + wn * 64;
#pragma unroll
    for (int m = 0; m < 4; ++m)
#pragma unroll
        for (int n = 0; n < 4; ++n)
#pragma unroll
            for (int r = 0; r < 4; ++r) {
                long row = mbase + m * 16 + l4 * 4 + r;
                long col = nbase + n * 16 + l15;
                float val = acc[m][n][r];
                if constexpr (EPI == 0) {
                    int c = (int)col;
                    int which = c >> 10, hh = (c >> 6) & 15, dd = c & 63;
                    int bb = (int)(row >> 11), tt = (int)(row & 2047);
                    if (which == 2) {
                        vd[((long)(bb * 16 + hh) * 64 + dd) * 2048 + tt] = f2bf(val);
                    } else {
                        u16* dst = which == 0 ? qd : kd;
                        dst[((long)(bb * 16 + hh) * 2048 + tt) * 64 + dd] = f2bf(val);
                    }
                } else if constexpr (EPI == 1) {
                    outF[row * N + col] = val + bias[col] + resid[row * N + col];
                } else {
                    float t2 = val + bias[col];
                    outB[row * N + col] = f2bf(t2 > 0.f ? t2 : 0.f);
                }
            }
}

// ---------------------------------------------------------------------------
// Causal flash attention.  Block = (pair p, h, b): q-tiles {p, 15-p}, each
// 128 q rows (4 waves x 32).  Double-buffered K/V LDS, T14 async reg-stage,
// one barrier per k-tile.  Softmax in exp2 domain.
// ---------------------------------------------------------------------------
__global__ __launch_bounds__(256, 2) void attn_kernel(
    const u16* __restrict__ Q, const u16* __restrict__ K,
    const u16* __restrict__ Vt, u16* __restrict__ O)
{
    constexpr int PAD = 72;
    constexpr float SC2 = 0.125f * 1.44269504088896f;   // scale * log2(e)
    __shared__ alignas(16) u16 Ks[2][64 * PAD];
    __shared__ alignas(16) u16 Vts[2][64 * PAD];
    __shared__ alignas(16) u16 Ps[4 * 32 * PAD];
    int tid = threadIdx.x, lane = tid & 63, w = tid >> 6;
    int l15 = lane & 15, l4 = lane >> 4;
    int qp = blockIdx.x, hh = blockIdx.y, bb = blockIdx.z;
    const long hbase = ((long)(bb * 16 + hh)) * 2048 * 64;
    u16* pw = &Ps[w * 32 * PAD];

    // staging address components (per thread, 2 chunks each for K and V)
    int srow[2], scol8[2];
#pragma unroll
    for (int i = 0; i < 2; ++i) {
        int c = tid + 256 * i;
        srow[i] = c >> 3;
        scol8[i] = (c & 7) * 8;
    }

#pragma unroll 1
    for (int ph = 0; ph < 2; ++ph) {
        int qt = ph == 0 ? qp : 15 - qp;
        int q0w = qt * 128 + w * 32;
        int nt = 2 * qt + 2;

        s16x8 aq[2][2];
#pragma unroll
        for (int m = 0; m < 2; ++m)
#pragma unroll
            for (int kk = 0; kk < 2; ++kk)
                aq[m][kk] = *(const s16x8*)&Q[hbase + (long)(q0w + m * 16 + l15) * 64 + kk * 32 + l4 * 8];

        f32x4 o[2][4] = {};
        float mrow[2][4], lrow[2][4];
#pragma unroll
        for (int m = 0; m < 2; ++m)
#pragma unroll
            for (int r = 0; r < 4; ++r) { mrow[m][r] = -1e30f; lrow[m][r] = 0.f; }

        // ---- prologue: tile0 -> buf0 (direct), tile1 -> regs ----
        s16x8 kr[2], vr[2];
        {
            const u16* Kg = K + hbase;
            const u16* Vg = Vt + hbase;
#pragma unroll
            for (int i = 0; i < 2; ++i) {
                s16x8 k0 = *(const s16x8*)&Kg[srow[i] * 64 + scol8[i]];
                s16x8 v0 = *(const s16x8*)&Vg[(long)srow[i] * 2048 + scol8[i]];
                *(s16x8*)&Ks[0][srow[i] * PAD + scol8[i]]  = k0;
                *(s16x8*)&Vts[0][srow[i] * PAD + scol8[i]] = v0;
            }
            if (nt > 1) {
                const u16* Kg1 = K + hbase + 64 * 64;
                const u16* Vg1 = Vt + hbase + 64;
#pragma unroll
                for (int i = 0; i < 2; ++i) {
                    kr[i] = *(const s16x8*)&Kg1[srow[i] * 64 + scol8[i]];
                    vr[i] = *(const s16x8*)&Vg1[(long)srow[i] * 2048 + scol8[i]];
                }
            }
        }
        __syncthreads();

#pragma unroll 1
        for (int kt = 0; kt < nt; ++kt) {
            int cur = kt & 1;
            // write staged regs (tile kt+1) into the other buffer
            if (kt + 1 < nt) {
#pragma unroll
                for (int i = 0; i < 2; ++i) {
                    *(s16x8*)&Ks[cur ^ 1][srow[i] * PAD + scol8[i]]  = kr[i];
                    *(s16x8*)&Vts[cur ^ 1][srow[i] * PAD + scol8[i]] = vr[i];
                }
            }
            // issue loads for tile kt+2
            if (kt + 2 < nt) {
                const u16* Kg = K + hbase + (long)(kt + 2) * 64 * 64;
                const u16* Vg = Vt + hbase + (long)(kt + 2) * 64;
#pragma unroll
                for (int i = 0; i < 2; ++i) {
                    kr[i] = *(const s16x8*)&Kg[srow[i] * 64 + scol8[i]];
                    vr[i] = *(const s16x8*)&Vg[(long)srow[i] * 2048 + scol8[i]];
                }
            }

            // ---- compute on buf[cur] ----
            s16x8 bk[4][2];
#pragma unroll
            for (int n = 0; n < 4; ++n)
#pragma unroll
                for (int kk = 0; kk < 2; ++kk)
                    bk[n][kk] = *(const s16x8*)&Ks[cur][(n * 16 + l15) * PAD + kk * 32 + l4 * 8];

            bool needMask = (kt * 64 + 63 > q0w);
#pragma unroll
            for (int m = 0; m < 2; ++m) {
                f32x4 s[4];
                __builtin_amdgcn_s_setprio(1);
#pragma unroll
                for (int n = 0; n < 4; ++n) {
                    f32x4 z = {0.f, 0.f, 0.f, 0.f};
                    z = mfma16(aq[m][0], bk[n][0], z);
                    z = mfma16(aq[m][1], bk[n][1], z);
                    s[n] = z;
                }
                __builtin_amdgcn_s_setprio(0);
                float pm[4] = {-1e30f, -1e30f, -1e30f, -1e30f};
#pragma unroll
                for (int n = 0; n < 4; ++n)
#pragma unroll
                    for (int r = 0; r < 4; ++r) {
                        float sv = s[n][r] * SC2;          // exp2 domain
                        if (needMask) {
                            int kglob = kt * 64 + n * 16 + l15;
                            int qglob = q0w + m * 16 + l4 * 4 + r;
                            if (kglob > qglob) sv = -1e30f;
                        }
                        s[n][r] = sv;
                        pm[r] = fmaxf(pm[r], sv);
                    }
#pragma unroll
                for (int xm = 1; xm < 16; xm <<= 1)
#pragma unroll
                    for (int r = 0; r < 4; ++r) pm[r] = fmaxf(pm[r], __shfl_xor(pm[r], xm));

                float ef[4], rsum[4] = {0.f, 0.f, 0.f, 0.f};
#pragma unroll
                for (int r = 0; r < 4; ++r) {
                    float mn = fmaxf(mrow[m][r], pm[r]);
                    ef[r] = exp2f(mrow[m][r] - mn);
                    mrow[m][r] = mn;
                }
#pragma unroll
                for (int n = 0; n < 4; ++n)
#pragma unroll
                    for (int r = 0; r < 4; ++r) {
                        float p = exp2f(s[n][r] - mrow[m][r]);
                        s[n][r] = p;
                        rsum[r] += p;
                    }
#pragma unroll
                for (int xm = 1; xm < 16; xm <<= 1)
#pragma unroll
                    for (int r = 0; r < 4; ++r) rsum[r] += __shfl_xor(rsum[r], xm);
#pragma unroll
                for (int r = 0; r < 4; ++r) lrow[m][r] = lrow[m][r] * ef[r] + rsum[r];
#pragma unroll
                for (int n = 0; n < 4; ++n)
#pragma unroll
                    for (int r = 0; r < 4; ++r) o[m][n][r] *= ef[r];

#pragma unroll
                for (int n = 0; n < 4; ++n)
#pragma unroll
                    for (int r = 0; r < 4; ++r)
                        pw[(m * 16 + l4 * 4 + r) * PAD + n * 16 + l15] = f2bf(s[n][r]);
            }

            s16x8 pa[2][2], bv[4][2];
#pragma unroll
            for (int m = 0; m < 2; ++m)
#pragma unroll
                for (int kk = 0; kk < 2; ++kk)
                    pa[m][kk] = *(const s16x8*)&pw[(m * 16 + l15) * PAD + kk * 32 + l4 * 8];
#pragma unroll
            for (int n = 0; n < 4; ++n)
#pragma unroll
                for (int kk = 0; kk < 2; ++kk)
                    bv[n][kk] = *(const s16x8*)&Vts[cur][(n * 16 + l15) * PAD + kk * 32 + l4 * 8];
            __builtin_amdgcn_s_setprio(1);
#pragma unroll
            for (int m = 0; m < 2; ++m)
#pragma unroll
                for (int n = 0; n < 4; ++n) {
                    o[m][n] = mfma16(pa[m][0], bv[n][0], o[m][n]);
                    o[m][n] = mfma16(pa[m][1], bv[n][1], o[m][n]);
                }
            __builtin_amdgcn_s_setprio(0);
            __syncthreads();
        }

#pragma unroll
        for (int m = 0; m < 2; ++m) {
            float invl[4];
#pragma unroll
            for (int r = 0; r < 4; ++r) invl[r] = 1.0f / lrow[m][r];
#pragma unroll
            for (int n = 0; n < 4; ++n)
#pragma unroll
                for (int r = 0; r < 4; ++r) {
                    int t = q0w + m * 16 + l4 * 4 + r;
                    O[((long)(bb * 2048 + t)) * 1024 + hh * 64 + n * 16 + l15] =
                        f2bf(o[m][n][r] * invl[r]);
                }
        }
        __syncthreads();   // protect LDS before next phase's prologue writes
    }
}

// ---------------------------------------------------------------------------
extern "C" void kernel_launch(void* const* d_in, const int* in_sizes, int n_in,
                              void* d_out, int out_size, void* d_ws, size_t ws_size,
                              hipStream_t stream)
{
    const float* x      = (const float*)d_in[0];
    const float* wq     = (const float*)d_in[1];
    const float* wk     = (const float*)d_in[2];
    const float* wv     = (const float*)d_in[3];
    const float* w_proj = (const float*)d_in[4];
    const float* b_proj = (const float*)d_in[5];
    const float* w1     = (const float*)d_in[6];
    const float* b1     = (const float*)d_in[7];
    const float* w2     = (const float*)d_in[8];
    const float* b2     = (const float*)d_in[9];
    const float* ln1_g  = (const float*)d_in[10];
    const float* ln1_b  = (const float*)d_in[11];
    const float* ln2_g  = (const float*)d_in[12];
    const float* ln2_b  = (const float*)d_in[13];

    char* ws = (char*)d_ws;
    u16*   WQKVt = (u16*)(ws + 0);           // 3072x1024 bf16
    u16*   WPt   = (u16*)(ws + 6291456);     // 1024x1024
    u16*   W1t   = (u16*)(ws + 8388608);     // 4096x1024
    u16*   W2t   = (u16*)(ws + 16777216);    // 1024x4096
    u16*   H     = (u16*)(ws + 25165824);    // 8192x1024 (h, then h2)
    u16*   Qb    = (u16*)(ws + 41943040);    // [B,H,T,D]
    u16*   Kb    = (u16*)(ws + 58720256);    // [B,H,T,D]
    u16*   Vb    = (u16*)(ws + 75497472);    // [B,H,D,T]  (transposed)
    u16*   Ob    = (u16*)(ws + 92274688);    // [B,T,C]
    u16*   FF    = (u16*)(ws + 41943040);    // 8192x4096, overlaps Q..O
    float* X1    = (float*)(ws + 109051904); // 8192x1024 fp32
    float* out   = (float*)d_out;

    transpose_cvt<<<dim3(16, 1, 16), 256, 0, stream>>>(wq, WQKVt,           1024, 64, 65536, 65536);
    transpose_cvt<<<dim3(16, 1, 16), 256, 0, stream>>>(wk, WQKVt + 1048576, 1024, 64, 65536, 65536);
    transpose_cvt<<<dim3(16, 1, 16), 256, 0, stream>>>(wv, WQKVt + 2097152, 1024, 64, 65536, 65536);
    transpose_cvt<<<dim3(16, 16, 1), 256, 0, stream>>>(w_proj, WPt, 1024, 1024, 0, 0);
    transpose_cvt<<<dim3(16, 64, 1), 256, 0, stream>>>(w1, W1t, 1024, 4096, 0, 0);
    transpose_cvt<<<dim3(64, 16, 1), 256, 0, stream>>>(w2, W2t, 4096, 1024, 0, 0);

    ln_bf16<<<8192, 256, 0, stream>>>(x, ln1_g, ln1_b, H);

    gemm_bt<0><<<dim3(64, 24), 256, 0, stream>>>(H, WQKVt, 8192, 3072, 1024,
        nullptr, nullptr, nullptr, nullptr, Qb, Kb, Vb);

    attn_kernel<<<dim3(8, 16, 4), 256, 0, stream>>>(Qb, Kb, Vb, Ob);

    gemm_bt<1><<<dim3(64, 8), 256, 0, stream>>>(Ob, WPt, 8192, 1024, 1024,
        X1, nullptr, b_proj, x, nullptr, nullptr, nullptr);

    ln_bf16<<<8192, 256, 0, stream>>>(X1, ln2_g, ln2_b, H);

    gemm_bt<2><<<dim3(64, 32), 256, 0, stream>>>(H, W1t, 8192, 4096, 1024,
        nullptr, FF, b1, nullptr, nullptr, nullptr, nullptr);

    gemm_bt<1><<<dim3(64, 8), 256, 0, stream>>>(FF, W2t, 8192, 1024, 4096,
        out, nullptr, b2, X1, nullptr, nullptr, nullptr);
}

// Round 4
// 463.498 us; speedup vs baseline: 1.2895x; 1.0016x over previous
//
#include <hip/hip_runtime.h>

// ---------------------------------------------------------------------------
// TransformerBlock on MI355X (gfx950), bf16 MFMA internal compute.
// B=4 T=2048 C=1024 H=16 D=64 FF=4096. All fp32 I/O; bf16 internally.
//
// R3: attention VALU diet.
//  - native (__bf16) casts (RNE, 1 op, cvt_pk-pairable) replace bit-twiddle
//  - T13 defer-max (skip o-rescale when tile max doesn't grow past THR)
//  - P-LDS 16B-chunk swizzle chunk^=(q>>2)&3: kills 4-way P-write conflicts,
//    per-lane-constant on both sides, keeps b128 alignment
// ---------------------------------------------------------------------------

#define DEVI __device__ __forceinline__

typedef float  f32x4  __attribute__((ext_vector_type(4)));
typedef __bf16 bf16x8 __attribute__((ext_vector_type(8)));
typedef short  s16x8  __attribute__((ext_vector_type(8)));
typedef unsigned short u16;

DEVI u16 f2bf(float f) {            // native RNE fp32->bf16 (v_cvt_pk-able)
    return __builtin_bit_cast(u16, (__bf16)f);
}

DEVI void gload_lds16(const void* g, void* l) {
    __builtin_amdgcn_global_load_lds(
        (__attribute__((address_space(1))) void*)(g),
        (__attribute__((address_space(3))) void*)(l), 16, 0, 0);
}

DEVI f32x4 mfma16(s16x8 a, s16x8 b, f32x4 c) {
    return __builtin_amdgcn_mfma_f32_16x16x32_bf16(
        __builtin_bit_cast(bf16x8, a), __builtin_bit_cast(bf16x8, b), c, 0, 0, 0);
}

// ---------------------------------------------------------------------------
// Tiled transpose + fp32->bf16: dst[n][k] = src[k][n].  64x64 tile, 256 thr.
// ---------------------------------------------------------------------------
__global__ __launch_bounds__(256) void transpose_cvt(
    const float* __restrict__ src, u16* __restrict__ dst,
    int K, int N, long srcStride, long dstStride)
{
    __shared__ float t[64][65];
    src += (long)blockIdx.z * srcStride;
    dst += (long)blockIdx.z * dstStride;
    int k0 = blockIdx.x * 64, n0 = blockIdx.y * 64;
    int tx = threadIdx.x & 63, ty = threadIdx.x >> 6;
#pragma unroll
    for (int i = 0; i < 16; ++i) {
        int r = ty * 16 + i;
        t[r][tx] = src[(long)(k0 + r) * N + n0 + tx];
    }
    __syncthreads();
#pragma unroll
    for (int i = 0; i < 16; ++i) {
        int r = ty * 16 + i;
        dst[(long)(n0 + r) * K + k0 + tx] = f2bf(t[tx][r]);
    }
}

// ---------------------------------------------------------------------------
// LayerNorm row (C=1024) -> bf16.  1 row / block, 256 threads, float4 loads.
// ---------------------------------------------------------------------------
__global__ __launch_bounds__(256) void ln_bf16(
    const float* __restrict__ x, const float* __restrict__ g,
    const float* __restrict__ b, u16* __restrict__ out)
{
    int row = blockIdx.x, tid = threadIdx.x;
    const float4 v = ((const float4*)(x + (long)row * 1024))[tid];
    float s = v.x + v.y + v.z + v.w;
    float q = v.x * v.x + v.y * v.y + v.z * v.z + v.w * v.w;
#pragma unroll
    for (int m = 1; m < 64; m <<= 1) { s += __shfl_xor(s, m); q += __shfl_xor(q, m); }
    __shared__ float red[8];
    int lane = tid & 63, w = tid >> 6;
    if (lane == 0) { red[w] = s; red[w + 4] = q; }
    __syncthreads();
    s = red[0] + red[1] + red[2] + red[3];
    q = red[4] + red[5] + red[6] + red[7];
    float mu  = s * (1.0f / 1024.0f);
    float var = q * (1.0f / 1024.0f) - mu * mu;
    float rs  = rsqrtf(var + 1e-5f);
    float4 gv = ((const float4*)g)[tid];
    float4 bv = ((const float4*)b)[tid];
    ushort4 o;
    o.x = f2bf((v.x - mu) * rs * gv.x + bv.x);
    o.y = f2bf((v.y - mu) * rs * gv.y + bv.y);
    o.z = f2bf((v.z - mu) * rs * gv.z + bv.z);
    o.w = f2bf((v.w - mu) * rs * gv.w + bv.w);
    ((ushort4*)(out + (long)row * 1024))[tid] = o;
}

// ---------------------------------------------------------------------------
// GEMM: C[M,N] = A[M,K] * B[K,N], A row-major bf16, Bt = B^T [N][K] bf16.
// 128x128 tile, BK=32, 4 waves (2x2), 4x4 16x16x32 MFMA frags per wave.
// EPI: 0 = QKV scatter (V transposed!), 1 = +bias +resid -> fp32,
//      2 = relu(+bias) -> bf16
// ---------------------------------------------------------------------------
template <int EPI>
__global__ __launch_bounds__(256, 3) void gemm_bt(
    const u16* __restrict__ A, const u16* __restrict__ Bt,
    int M, int N, int K,
    float* __restrict__ outF, u16* __restrict__ outB,
    const float* __restrict__ bias, const float* __restrict__ resid,
    u16* __restrict__ qd, u16* __restrict__ kd, u16* __restrict__ vd)
{
    __shared__ alignas(16) u16 As[128 * 32];
    __shared__ alignas(16) u16 Bs[128 * 32];
    int tid = threadIdx.x;
    int lane = tid & 63, w = tid >> 6;
    int wm = w & 1, wn = w >> 1;
    int l15 = lane & 15, l4 = lane >> 4;
    long m0 = (long)blockIdx.x * 128, n0 = (long)blockIdx.y * 128;
    const u16* Ag = A + m0 * K;
    const u16* Bg = Bt + n0 * K;
    int scol = (lane & 3) * 8;
    int srow0 = (w * 2 + 0) * 16 + (lane >> 2);
    int srow1 = (w * 2 + 1) * 16 + (lane >> 2);

    f32x4 acc[4][4] = {};

    for (int kt = 0; kt < K; kt += 32) {
        gload_lds16(Ag + (long)srow0 * K + kt + scol, &As[(w * 2 + 0) * 512]);
        gload_lds16(Ag + (long)srow1 * K + kt + scol, &As[(w * 2 + 1) * 512]);
        gload_lds16(Bg + (long)srow0 * K + kt + scol, &Bs[(w * 2 + 0) * 512]);
        gload_lds16(Bg + (long)srow1 * K + kt + scol, &Bs[(w * 2 + 1) * 512]);
        __syncthreads();
        s16x8 a[4], b[4];
#pragma unroll
        for (int m = 0; m < 4; ++m)
            a[m] = *(const s16x8*)&As[(wm * 64 + m * 16 + l15) * 32 + l4 * 8];
#pragma unroll
        for (int n = 0; n < 4; ++n)
            b[n] = *(const s16x8*)&Bs[(wn * 64 + n * 16 + l15) * 32 + l4 * 8];
#pragma unroll
        for (int m = 0; m < 4; ++m)
#pragma unroll
            for (int n = 0; n < 4; ++n)
                acc[m][n] = mfma16(a[m], b[n], acc[m][n]);
        __syncthreads();
    }

    long mbase = m0 + wm * 64;
    long nbase = n0 + wn * 64;
#pragma unroll
    for (int m = 0; m < 4; ++m)
#pragma unroll
        for (int n = 0; n < 4; ++n)
#pragma unroll
            for (int r = 0; r < 4; ++r) {
                long row = mbase + m * 16 + l4 * 4 + r;
                long col = nbase + n * 16 + l15;
                float val = acc[m][n][r];
                if constexpr (EPI == 0) {
                    int c = (int)col;
                    int which = c >> 10, hh = (c >> 6) & 15, dd = c & 63;
                    int bb = (int)(row >> 11), tt = (int)(row & 2047);
                    if (which == 2) {
                        vd[((long)(bb * 16 + hh) * 64 + dd) * 2048 + tt] = f2bf(val);
                    } else {
                        u16* dst = which == 0 ? qd : kd;
                        dst[((long)(bb * 16 + hh) * 2048 + tt) * 64 + dd] = f2bf(val);
                    }
                } else if constexpr (EPI == 1) {
                    outF[row * N + col] = val + bias[col] + resid[row * N + col];
                } else {
                    float t2 = val + bias[col];
                    outB[row * N + col] = f2bf(t2 > 0.f ? t2 : 0.f);
                }
            }
}

// ---------------------------------------------------------------------------
// Causal flash attention.  Block = (pair p, h, b): q-tiles {p, 15-p}, each
// 128 q rows (4 waves x 32).  Double-buffered K/V LDS, T14 async reg-stage,
// one barrier per k-tile.  exp2-domain softmax + T13 defer-max.
// P LDS swizzled at 16B-chunk granularity: chunk ^= (q>>2)&3.
// ---------------------------------------------------------------------------
__global__ __launch_bounds__(256, 2) void attn_kernel(
    const u16* __restrict__ Q, const u16* __restrict__ K,
    const u16* __restrict__ Vt, u16* __restrict__ O)
{
    constexpr int PAD = 72;
    constexpr float SC2 = 0.125f * 1.44269504088896f;   // scale * log2(e)
    constexpr float THR = 11.5416f;                     // 8 * log2(e)
    __shared__ alignas(16) u16 Ks[2][64 * PAD];
    __shared__ alignas(16) u16 Vts[2][64 * PAD];
    __shared__ alignas(16) u16 Ps[4 * 32 * PAD];
    int tid = threadIdx.x, lane = tid & 63, w = tid >> 6;
    int l15 = lane & 15, l4 = lane >> 4;
    int qp = blockIdx.x, hh = blockIdx.y, bb = blockIdx.z;
    const long hbase = ((long)(bb * 16 + hh)) * 2048 * 64;
    u16* pw = &Ps[w * 32 * PAD];
    int rdswz = (l15 >> 2) & 3;            // read-side chunk xor (q'=m16+l15)

    int srow[2], scol8[2];
#pragma unroll
    for (int i = 0; i < 2; ++i) {
        int c = tid + 256 * i;
        srow[i] = c >> 3;
        scol8[i] = (c & 7) * 8;
    }

#pragma unroll 1
    for (int ph = 0; ph < 2; ++ph) {
        int qt = ph == 0 ? qp : 15 - qp;
        int q0w = qt * 128 + w * 32;
        int nt = 2 * qt + 2;

        s16x8 aq[2][2];
#pragma unroll
        for (int m = 0; m < 2; ++m)
#pragma unroll
            for (int kk = 0; kk < 2; ++kk)
                aq[m][kk] = *(const s16x8*)&Q[hbase + (long)(q0w + m * 16 + l15) * 64 + kk * 32 + l4 * 8];

        f32x4 o[2][4] = {};
        float mrow[2][4], lrow[2][4];
#pragma unroll
        for (int m = 0; m < 2; ++m)
#pragma unroll
            for (int r = 0; r < 4; ++r) { mrow[m][r] = -1e30f; lrow[m][r] = 0.f; }

        // ---- prologue: tile0 -> buf0 (direct), tile1 -> regs ----
        s16x8 kr[2], vr[2];
        {
            const u16* Kg = K + hbase;
            const u16* Vg = Vt + hbase;
#pragma unroll
            for (int i = 0; i < 2; ++i) {
                s16x8 k0 = *(const s16x8*)&Kg[srow[i] * 64 + scol8[i]];
                s16x8 v0 = *(const s16x8*)&Vg[(long)srow[i] * 2048 + scol8[i]];
                *(s16x8*)&Ks[0][srow[i] * PAD + scol8[i]]  = k0;
                *(s16x8*)&Vts[0][srow[i] * PAD + scol8[i]] = v0;
            }
            if (nt > 1) {
                const u16* Kg1 = K + hbase + 64 * 64;
                const u16* Vg1 = Vt + hbase + 64;
#pragma unroll
                for (int i = 0; i < 2; ++i) {
                    kr[i] = *(const s16x8*)&Kg1[srow[i] * 64 + scol8[i]];
                    vr[i] = *(const s16x8*)&Vg1[(long)srow[i] * 2048 + scol8[i]];
                }
            }
        }
        __syncthreads();

#pragma unroll 1
        for (int kt = 0; kt < nt; ++kt) {
            int cur = kt & 1;
            if (kt + 1 < nt) {
#pragma unroll
                for (int i = 0; i < 2; ++i) {
                    *(s16x8*)&Ks[cur ^ 1][srow[i] * PAD + scol8[i]]  = kr[i];
                    *(s16x8*)&Vts[cur ^ 1][srow[i] * PAD + scol8[i]] = vr[i];
                }
            }
            if (kt + 2 < nt) {
                const u16* Kg = K + hbase + (long)(kt + 2) * 64 * 64;
                const u16* Vg = Vt + hbase + (long)(kt + 2) * 64;
#pragma unroll
                for (int i = 0; i < 2; ++i) {
                    kr[i] = *(const s16x8*)&Kg[srow[i] * 64 + scol8[i]];
                    vr[i] = *(const s16x8*)&Vg[(long)srow[i] * 2048 + scol8[i]];
                }
            }

            s16x8 bk[4][2];
#pragma unroll
            for (int n = 0; n < 4; ++n)
#pragma unroll
                for (int kk = 0; kk < 2; ++kk)
                    bk[n][kk] = *(const s16x8*)&Ks[cur][(n * 16 + l15) * PAD + kk * 32 + l4 * 8];

            bool needMask = (kt * 64 + 63 > q0w);
#pragma unroll
            for (int m = 0; m < 2; ++m) {
                f32x4 s[4];
                __builtin_amdgcn_s_setprio(1);
#pragma unroll
                for (int n = 0; n < 4; ++n) {
                    f32x4 z = {0.f, 0.f, 0.f, 0.f};
                    z = mfma16(aq[m][0], bk[n][0], z);
                    z = mfma16(aq[m][1], bk[n][1], z);
                    s[n] = z;
                }
                __builtin_amdgcn_s_setprio(0);
                float pm[4] = {-1e30f, -1e30f, -1e30f, -1e30f};
#pragma unroll
                for (int n = 0; n < 4; ++n)
#pragma unroll
                    for (int r = 0; r < 4; ++r) {
                        float sv = s[n][r] * SC2;          // exp2 domain
                        if (needMask) {
                            int kglob = kt * 64 + n * 16 + l15;
                            int qglob = q0w + m * 16 + l4 * 4 + r;
                            if (kglob > qglob) sv = -1e30f;
                        }
                        s[n][r] = sv;
                        pm[r] = fmaxf(pm[r], sv);
                    }
#pragma unroll
                for (int xm = 1; xm < 16; xm <<= 1)
#pragma unroll
                    for (int r = 0; r < 4; ++r) pm[r] = fmaxf(pm[r], __shfl_xor(pm[r], xm));

                // T13 defer-max: only rescale when tile max grew past THR
                bool okl = true;
#pragma unroll
                for (int r = 0; r < 4; ++r) okl = okl && (pm[r] - mrow[m][r] <= THR);
                int allok = __all(okl);
                float ef[4];
                if (!allok) {
#pragma unroll
                    for (int r = 0; r < 4; ++r) {
                        float mn = fmaxf(mrow[m][r], pm[r]);
                        ef[r] = exp2f(mrow[m][r] - mn);
                        mrow[m][r] = mn;
                    }
                }
                float rsum[4] = {0.f, 0.f, 0.f, 0.f};
#pragma unroll
                for (int n = 0; n < 4; ++n)
#pragma unroll
                    for (int r = 0; r < 4; ++r) {
                        float p = exp2f(s[n][r] - mrow[m][r]);
                        s[n][r] = p;
                        rsum[r] += p;
                    }
#pragma unroll
                for (int xm = 1; xm < 16; xm <<= 1)
#pragma unroll
                    for (int r = 0; r < 4; ++r) rsum[r] += __shfl_xor(rsum[r], xm);
                if (!allok) {
#pragma unroll
                    for (int r = 0; r < 4; ++r) lrow[m][r] = lrow[m][r] * ef[r] + rsum[r];
#pragma unroll
                    for (int n = 0; n < 4; ++n)
#pragma unroll
                        for (int r = 0; r < 4; ++r) o[m][n][r] *= ef[r];
                } else {
#pragma unroll
                    for (int r = 0; r < 4; ++r) lrow[m][r] += rsum[r];
                }

                // P write, swizzled: row q=m16+l4*4+r, col n*16+l15,
                // chunk' = (n*2 + (l15>>3)) ^ l4   (xor = (q>>2)&3 = l4)
#pragma unroll
                for (int n = 0; n < 4; ++n) {
                    int chunkp = ((n * 2 + (l15 >> 3)) ^ l4) * 8 + (l15 & 7);
#pragma unroll
                    for (int r = 0; r < 4; ++r)
                        pw[(m * 16 + l4 * 4 + r) * PAD + chunkp] = f2bf(s[n][r]);
                }
            }

            // PV: pa reads swizzled (xor = (q'>>2)&3 = (l15>>2)&3)
            s16x8 pa[2][2], bv[4][2];
#pragma unroll
            for (int m = 0; m < 2; ++m)
#pragma unroll
                for (int kk = 0; kk < 2; ++kk)
                    pa[m][kk] = *(const s16x8*)&pw[(m * 16 + l15) * PAD + (kk * 4 + (l4 ^ rdswz)) * 8];
#pragma unroll
            for (int n = 0; n < 4; ++n)
#pragma unroll
                for (int kk = 0; kk < 2; ++kk)
                    bv[n][kk] = *(const s16x8*)&Vts[cur][(n * 16 + l15) * PAD + kk * 32 + l4 * 8];
            __builtin_amdgcn_s_setprio(1);
#pragma unroll
            for (int m = 0; m < 2; ++m)
#pragma unroll
                for (int n = 0; n < 4; ++n) {
                    o[m][n] = mfma16(pa[m][0], bv[n][0], o[m][n]);
                    o[m][n] = mfma16(pa[m][1], bv[n][1], o[m][n]);
                }
            __builtin_amdgcn_s_setprio(0);
            __syncthreads();
        }

#pragma unroll
        for (int m = 0; m < 2; ++m) {
            float invl[4];
#pragma unroll
            for (int r = 0; r < 4; ++r) invl[r] = 1.0f / lrow[m][r];
#pragma unroll
            for (int n = 0; n < 4; ++n)
#pragma unroll
                for (int r = 0; r < 4; ++r) {
                    int t = q0w + m * 16 + l4 * 4 + r;
                    O[((long)(bb * 2048 + t)) * 1024 + hh * 64 + n * 16 + l15] =
                        f2bf(o[m][n][r] * invl[r]);
                }
        }
        __syncthreads();   // protect LDS before next phase's prologue writes
    }
}

// ---------------------------------------------------------------------------
extern "C" void kernel_launch(void* const* d_in, const int* in_sizes, int n_in,
                              void* d_out, int out_size, void* d_ws, size_t ws_size,
                              hipStream_t stream)
{
    const float* x      = (const float*)d_in[0];
    const float* wq     = (const float*)d_in[1];
    const float* wk     = (const float*)d_in[2];
    const float* wv     = (const float*)d_in[3];
    const float* w_proj = (const float*)d_in[4];
    const float* b_proj = (const float*)d_in[5];
    const float* w1     = (const float*)d_in[6];
    const float* b1     = (const float*)d_in[7];
    const float* w2     = (const float*)d_in[8];
    const float* b2     = (const float*)d_in[9];
    const float* ln1_g  = (const float*)d_in[10];
    const float* ln1_b  = (const float*)d_in[11];
    const float* ln2_g  = (const float*)d_in[12];
    const float* ln2_b  = (const float*)d_in[13];

    char* ws = (char*)d_ws;
    u16*   WQKVt = (u16*)(ws + 0);           // 3072x1024 bf16
    u16*   WPt   = (u16*)(ws + 6291456);     // 1024x1024
    u16*   W1t   = (u16*)(ws + 8388608);     // 4096x1024
    u16*   W2t   = (u16*)(ws + 16777216);    // 1024x4096
    u16*   H     = (u16*)(ws + 25165824);    // 8192x1024 (h, then h2)
    u16*   Qb    = (u16*)(ws + 41943040);    // [B,H,T,D]
    u16*   Kb    = (u16*)(ws + 58720256);    // [B,H,T,D]
    u16*   Vb    = (u16*)(ws + 75497472);    // [B,H,D,T]  (transposed)
    u16*   Ob    = (u16*)(ws + 92274688);    // [B,T,C]
    u16*   FF    = (u16*)(ws + 41943040);    // 8192x4096, overlaps Q..O
    float* X1    = (float*)(ws + 109051904); // 8192x1024 fp32
    float* out   = (float*)d_out;

    transpose_cvt<<<dim3(16, 1, 16), 256, 0, stream>>>(wq, WQKVt,           1024, 64, 65536, 65536);
    transpose_cvt<<<dim3(16, 1, 16), 256, 0, stream>>>(wk, WQKVt + 1048576, 1024, 64, 65536, 65536);
    transpose_cvt<<<dim3(16, 1, 16), 256, 0, stream>>>(wv, WQKVt + 2097152, 1024, 64, 65536, 65536);
    transpose_cvt<<<dim3(16, 16, 1), 256, 0, stream>>>(w_proj, WPt, 1024, 1024, 0, 0);
    transpose_cvt<<<dim3(16, 64, 1), 256, 0, stream>>>(w1, W1t, 1024, 4096, 0, 0);
    transpose_cvt<<<dim3(64, 16, 1), 256, 0, stream>>>(w2, W2t, 4096, 1024, 0, 0);

    ln_bf16<<<8192, 256, 0, stream>>>(x, ln1_g, ln1_b, H);

    gemm_bt<0><<<dim3(64, 24), 256, 0, stream>>>(H, WQKVt, 8192, 3072, 1024,
        nullptr, nullptr, nullptr, nullptr, Qb, Kb, Vb);

    attn_kernel<<<dim3(8, 16, 4), 256, 0, stream>>>(Qb, Kb, Vb, Ob);

    gemm_bt<1><<<dim3(64, 8), 256, 0, stream>>>(Ob, WPt, 8192, 1024, 1024,
        X1, nullptr, b_proj, x, nullptr, nullptr, nullptr);

    ln_bf16<<<8192, 256, 0, stream>>>(X1, ln2_g, ln2_b, H);

    gemm_bt<2><<<dim3(64, 32), 256, 0, stream>>>(H, W1t, 8192, 4096, 1024,
        nullptr, FF, b1, nullptr, nullptr, nullptr, nullptr);

    gemm_bt<1><<<dim3(64, 8), 256, 0, stream>>>(FF, W2t, 8192, 1024, 4096,
        out, nullptr, b2, X1, nullptr, nullptr, nullptr);
}

// Round 6
// 427.705 us; speedup vs baseline: 1.3974x; 1.0837x over previous
//
#include <hip/hip_runtime.h>

// ---------------------------------------------------------------------------
// TransformerBlock on MI355X (gfx950), bf16 MFMA internal compute.
// B=4 T=2048 C=1024 H=16 D=64 FF=4096. All fp32 I/O; bf16 internally.
//
// R5: R4's swapped-operand 32x32 attention, with the P->A-frag repack
// rebuilt from verified primitives (f2bf pack + __shfl_xor(32) + select)
// instead of hand-asm cvt_pk/permlane32_swap (suspected R4 bug: swap
// direction unverified).
// ---------------------------------------------------------------------------

#define DEVI __device__ __forceinline__

typedef float  f32x4  __attribute__((ext_vector_type(4)));
typedef float  f32x16 __attribute__((ext_vector_type(16)));
typedef __bf16 bf16x8 __attribute__((ext_vector_type(8)));
typedef short  s16x8  __attribute__((ext_vector_type(8)));
typedef unsigned int u32x4 __attribute__((ext_vector_type(4)));
typedef unsigned short u16;

DEVI u16 f2bf(float f) {            // native RNE fp32->bf16
    return __builtin_bit_cast(u16, (__bf16)f);
}

DEVI unsigned pk2(float lo, float hi2) {    // {bf16(lo), bf16(hi2)} dword
    return (unsigned)f2bf(lo) | ((unsigned)f2bf(hi2) << 16);
}

DEVI void gload_lds16(const void* g, void* l) {
    __builtin_amdgcn_global_load_lds(
        (__attribute__((address_space(1))) void*)(g),
        (__attribute__((address_space(3))) void*)(l), 16, 0, 0);
}

DEVI f32x4 mfma16(s16x8 a, s16x8 b, f32x4 c) {
    return __builtin_amdgcn_mfma_f32_16x16x32_bf16(
        __builtin_bit_cast(bf16x8, a), __builtin_bit_cast(bf16x8, b), c, 0, 0, 0);
}

DEVI f32x16 mfma32(s16x8 a, s16x8 b, f32x16 c) {
    return __builtin_amdgcn_mfma_f32_32x32x16_bf16(
        __builtin_bit_cast(bf16x8, a), __builtin_bit_cast(bf16x8, b), c, 0, 0, 0);
}

// ---------------------------------------------------------------------------
// Tiled transpose + fp32->bf16: dst[n][k] = src[k][n].  64x64 tile, 256 thr.
// ---------------------------------------------------------------------------
__global__ __launch_bounds__(256) void transpose_cvt(
    const float* __restrict__ src, u16* __restrict__ dst,
    int K, int N, long srcStride, long dstStride)
{
    __shared__ float t[64][65];
    src += (long)blockIdx.z * srcStride;
    dst += (long)blockIdx.z * dstStride;
    int k0 = blockIdx.x * 64, n0 = blockIdx.y * 64;
    int tx = threadIdx.x & 63, ty = threadIdx.x >> 6;
#pragma unroll
    for (int i = 0; i < 16; ++i) {
        int r = ty * 16 + i;
        t[r][tx] = src[(long)(k0 + r) * N + n0 + tx];
    }
    __syncthreads();
#pragma unroll
    for (int i = 0; i < 16; ++i) {
        int r = ty * 16 + i;
        dst[(long)(n0 + r) * K + k0 + tx] = f2bf(t[tx][r]);
    }
}

// ---------------------------------------------------------------------------
// LayerNorm row (C=1024) -> bf16.  1 row / block, 256 threads, float4 loads.
// ---------------------------------------------------------------------------
__global__ __launch_bounds__(256) void ln_bf16(
    const float* __restrict__ x, const float* __restrict__ g,
    const float* __restrict__ b, u16* __restrict__ out)
{
    int row = blockIdx.x, tid = threadIdx.x;
    const float4 v = ((const float4*)(x + (long)row * 1024))[tid];
    float s = v.x + v.y + v.z + v.w;
    float q = v.x * v.x + v.y * v.y + v.z * v.z + v.w * v.w;
#pragma unroll
    for (int m = 1; m < 64; m <<= 1) { s += __shfl_xor(s, m); q += __shfl_xor(q, m); }
    __shared__ float red[8];
    int lane = tid & 63, w = tid >> 6;
    if (lane == 0) { red[w] = s; red[w + 4] = q; }
    __syncthreads();
    s = red[0] + red[1] + red[2] + red[3];
    q = red[4] + red[5] + red[6] + red[7];
    float mu  = s * (1.0f / 1024.0f);
    float var = q * (1.0f / 1024.0f) - mu * mu;
    float rs  = rsqrtf(var + 1e-5f);
    float4 gv = ((const float4*)g)[tid];
    float4 bv = ((const float4*)b)[tid];
    ushort4 o;
    o.x = f2bf((v.x - mu) * rs * gv.x + bv.x);
    o.y = f2bf((v.y - mu) * rs * gv.y + bv.y);
    o.z = f2bf((v.z - mu) * rs * gv.z + bv.z);
    o.w = f2bf((v.w - mu) * rs * gv.w + bv.w);
    ((ushort4*)(out + (long)row * 1024))[tid] = o;
}

// ---------------------------------------------------------------------------
// GEMM: C[M,N] = A[M,K] * B[K,N], A row-major bf16, Bt = B^T [N][K] bf16.
// 128x128 tile, BK=32, 4 waves (2x2), 4x4 16x16x32 MFMA frags per wave.
// EPI: 0 = QKV scatter (V transposed!), 1 = +bias +resid -> fp32,
//      2 = relu(+bias) -> bf16
// ---------------------------------------------------------------------------
template <int EPI>
__global__ __launch_bounds__(256, 3) void gemm_bt(
    const u16* __restrict__ A, const u16* __restrict__ Bt,
    int M, int N, int K,
    float* __restrict__ outF, u16* __restrict__ outB,
    const float* __restrict__ bias, const float* __restrict__ resid,
    u16* __restrict__ qd, u16* __restrict__ kd, u16* __restrict__ vd)
{
    __shared__ alignas(16) u16 As[128 * 32];
    __shared__ alignas(16) u16 Bs[128 * 32];
    int tid = threadIdx.x;
    int lane = tid & 63, w = tid >> 6;
    int wm = w & 1, wn = w >> 1;
    int l15 = lane & 15, l4 = lane >> 4;
    long m0 = (long)blockIdx.x * 128, n0 = (long)blockIdx.y * 128;
    const u16* Ag = A + m0 * K;
    const u16* Bg = Bt + n0 * K;
    int scol = (lane & 3) * 8;
    int srow0 = (w * 2 + 0) * 16 + (lane >> 2);
    int srow1 = (w * 2 + 1) * 16 + (lane >> 2);

    f32x4 acc[4][4] = {};

    for (int kt = 0; kt < K; kt += 32) {
        gload_lds16(Ag + (long)srow0 * K + kt + scol, &As[(w * 2 + 0) * 512]);
        gload_lds16(Ag + (long)srow1 * K + kt + scol, &As[(w * 2 + 1) * 512]);
        gload_lds16(Bg + (long)srow0 * K + kt + scol, &Bs[(w * 2 + 0) * 512]);
        gload_lds16(Bg + (long)srow1 * K + kt + scol, &Bs[(w * 2 + 1) * 512]);
        __syncthreads();
        s16x8 a[4], b[4];
#pragma unroll
        for (int m = 0; m < 4; ++m)
            a[m] = *(const s16x8*)&As[(wm * 64 + m * 16 + l15) * 32 + l4 * 8];
#pragma unroll
        for (int n = 0; n < 4; ++n)
            b[n] = *(const s16x8*)&Bs[(wn * 64 + n * 16 + l15) * 32 + l4 * 8];
#pragma unroll
        for (int m = 0; m < 4; ++m)
#pragma unroll
            for (int n = 0; n < 4; ++n)
                acc[m][n] = mfma16(a[m], b[n], acc[m][n]);
        __syncthreads();
    }

    long mbase = m0 + wm * 64;
    long nbase = n0 + wn * 64;
#pragma unroll
    for (int m = 0; m < 4; ++m)
#pragma unroll
        for (int n = 0; n < 4; ++n)
#pragma unroll
            for (int r = 0; r < 4; ++r) {
                long row = mbase + m * 16 + l4 * 4 + r;
                long col = nbase + n * 16 + l15;
                float val = acc[m][n][r];
                if constexpr (EPI == 0) {
                    int c = (int)col;
                    int which = c >> 10, hh = (c >> 6) & 15, dd = c & 63;
                    int bb = (int)(row >> 11), tt = (int)(row & 2047);
                    if (which == 2) {
                        vd[((long)(bb * 16 + hh) * 64 + dd) * 2048 + tt] = f2bf(val);
                    } else {
                        u16* dst = which == 0 ? qd : kd;
                        dst[((long)(bb * 16 + hh) * 2048 + tt) * 64 + dd] = f2bf(val);
                    }
                } else if constexpr (EPI == 1) {
                    outF[row * N + col] = val + bias[col] + resid[row * N + col];
                } else {
                    float t2 = val + bias[col];
                    outB[row * N + col] = f2bf(t2 > 0.f ? t2 : 0.f);
                }
            }
}

// ---------------------------------------------------------------------------
// Causal flash attention, swapped-operand 32x32 MFMA.
// Block = (pair p, h, b): q-tiles {p, 15-p}, 4 waves x 32 q rows.
// S^T = mfma32(K,Q): lane l31 = q (col), regs = k (row=(r&3)+8(r>>2)+4hi).
// Softmax in-lane tree + 1 shfl_xor(32); m/l per-lane scalars.
// P->A-frag: f2bf pair-pack + 8x shfl_xor(32) + per-lane select.
// K [s][d] and V^T [d][s] in LDS (PAD=72), double-buffered, reg-staged.
// ---------------------------------------------------------------------------
__global__ __launch_bounds__(256, 4) void attn_kernel(
    const u16* __restrict__ Q, const u16* __restrict__ K,
    const u16* __restrict__ Vt, u16* __restrict__ O)
{
    constexpr int PAD = 72;
    constexpr float SC2 = 0.125f * 1.44269504088896f;   // scale * log2(e)
    constexpr float THR = 11.5416f;                     // 8 * log2(e)
    __shared__ alignas(16) u16 Ks[2][64 * PAD];
    __shared__ alignas(16) u16 Vts[2][64 * PAD];
    __shared__ alignas(16) float xbuf[4][32];           // per-wave bounce
    int tid = threadIdx.x, lane = tid & 63, w = tid >> 6;
    int l31 = lane & 31, hi = lane >> 5;
    bool h = (hi != 0);
    int qp = blockIdx.x, hh = blockIdx.y, bb = blockIdx.z;
    const long hbase = ((long)(bb * 16 + hh)) * 2048 * 64;

    int srow[2], scol8[2];
#pragma unroll
    for (int i = 0; i < 2; ++i) {
        int c = tid + 256 * i;
        srow[i] = c >> 3;
        scol8[i] = (c & 7) * 8;
    }

#pragma unroll 1
    for (int ph = 0; ph < 2; ++ph) {
        int qt = ph == 0 ? qp : 15 - qp;
        int q0w = qt * 128 + w * 32;
        int nt = 2 * qt + 2;
        int qv = q0w + l31;                 // this lane's q row

        // Q b-frags: b[j] = Q[q0w+l31][c*16 + hi*8 + j]
        s16x8 bq[4];
#pragma unroll
        for (int c = 0; c < 4; ++c)
            bq[c] = *(const s16x8*)&Q[hbase + (long)(q0w + l31) * 64 + c * 16 + hi * 8];

        f32x16 o0 = {}, o1 = {};            // O[q=crow][d=l31 | 32+l31]
        float mrow = -1e30f, lrow = 0.f;

        // ---- prologue: tile0 -> buf0 (direct), tile1 -> regs ----
        s16x8 kr[2], vr[2];
        {
            const u16* Kg = K + hbase;
            const u16* Vg = Vt + hbase;
#pragma unroll
            for (int i = 0; i < 2; ++i) {
                s16x8 k0 = *(const s16x8*)&Kg[srow[i] * 64 + scol8[i]];
                s16x8 v0 = *(const s16x8*)&Vg[(long)srow[i] * 2048 + scol8[i]];
                *(s16x8*)&Ks[0][srow[i] * PAD + scol8[i]]  = k0;
                *(s16x8*)&Vts[0][srow[i] * PAD + scol8[i]] = v0;
            }
            if (nt > 1) {
                const u16* Kg1 = K + hbase + 64 * 64;
                const u16* Vg1 = Vt + hbase + 64;
#pragma unroll
                for (int i = 0; i < 2; ++i) {
                    kr[i] = *(const s16x8*)&Kg1[srow[i] * 64 + scol8[i]];
                    vr[i] = *(const s16x8*)&Vg1[(long)srow[i] * 2048 + scol8[i]];
                }
            }
        }
        __syncthreads();

#pragma unroll 1
        for (int kt = 0; kt < nt; ++kt) {
            int cur = kt & 1;
            if (kt + 1 < nt) {
#pragma unroll
                for (int i = 0; i < 2; ++i) {
                    *(s16x8*)&Ks[cur ^ 1][srow[i] * PAD + scol8[i]]  = kr[i];
                    *(s16x8*)&Vts[cur ^ 1][srow[i] * PAD + scol8[i]] = vr[i];
                }
            }
            if (kt + 2 < nt) {
                const u16* Kg = K + hbase + (long)(kt + 2) * 64 * 64;
                const u16* Vg = Vt + hbase + (long)(kt + 2) * 64;
#pragma unroll
                for (int i = 0; i < 2; ++i) {
                    kr[i] = *(const s16x8*)&Kg[srow[i] * 64 + scol8[i]];
                    vr[i] = *(const s16x8*)&Vg[(long)srow[i] * 2048 + scol8[i]];
                }
            }

#pragma unroll
            for (int k2 = 0; k2 < 2; ++k2) {
                int kbase = kt * 64 + k2 * 32;
                if (kbase <= q0w + 31) {    // else fully masked for this wave
                    // --- S^T = K * Q^T over D=64 (4 chunks of 16) ---
                    f32x16 s = {};
                    __builtin_amdgcn_s_setprio(1);
#pragma unroll
                    for (int c = 0; c < 4; ++c) {
                        s16x8 ak = *(const s16x8*)&Ks[cur][(k2 * 32 + l31) * PAD + c * 16 + hi * 8];
                        s = mfma32(ak, bq[c], s);
                    }
                    __builtin_amdgcn_s_setprio(0);

                    // --- scale + causal mask (k = kbase + crow(r,hi)) ---
                    int khi = kbase + 4 * hi;
                    if (kbase + 31 > q0w) {
#pragma unroll
                        for (int r = 0; r < 16; ++r) {
                            int kg = khi + ((r & 3) + 8 * (r >> 2));
                            float sv = s[r] * SC2;
                            s[r] = (kg > qv) ? -1e30f : sv;
                        }
                    } else {
#pragma unroll
                        for (int r = 0; r < 16; ++r) s[r] *= SC2;
                    }

                    // --- row max: in-lane tree + hi-swap ---
                    float t8[8], t4[4], t2[2];
#pragma unroll
                    for (int r = 0; r < 8; ++r) t8[r] = fmaxf(s[r], s[r + 8]);
#pragma unroll
                    for (int r = 0; r < 4; ++r) t4[r] = fmaxf(t8[r], t8[r + 4]);
                    t2[0] = fmaxf(t4[0], t4[2]); t2[1] = fmaxf(t4[1], t4[3]);
                    float pm = fmaxf(t2[0], t2[1]);
                    pm = fmaxf(pm, __shfl_xor(pm, 32));

                    // --- T13 defer-max ---
                    int allok = __all(pm - mrow <= THR);
                    float ef = 1.f;
                    if (!allok) {
                        float mn = fmaxf(mrow, pm);
                        ef = exp2f(mrow - mn);
                        mrow = mn;
                    }
                    // --- exp2 + row sum ---
                    float a8[8], a4[4];
#pragma unroll
                    for (int r = 0; r < 16; ++r) s[r] = exp2f(s[r] - mrow);
#pragma unroll
                    for (int r = 0; r < 8; ++r) a8[r] = s[r] + s[r + 8];
#pragma unroll
                    for (int r = 0; r < 4; ++r) a4[r] = a8[r] + a8[r + 4];
                    float rsum = (a4[0] + a4[1]) + (a4[2] + a4[3]);
                    rsum += __shfl_xor(rsum, 32);

                    if (!allok) {
                        lrow = lrow * ef + rsum;
                        xbuf[w][l31] = ef;
#pragma unroll
                        for (int rr = 0; rr < 4; ++rr) {
                            f32x4 efv = *(const f32x4*)&xbuf[w][rr * 8 + hi * 4];
#pragma unroll
                            for (int j = 0; j < 4; ++j) {
                                o0[rr * 4 + j] *= efv[j];
                                o1[rr * 4 + j] *= efv[j];
                            }
                        }
                    } else {
                        lrow += rsum;
                    }

                    // --- P -> bf16 A-frags: pack + shfl_xor(32) + select ---
                    // lane (hi) holds dword ci = P[q=l31][k={2i + 4hi + (i>=2?4:0)...}]
                    // explicitly: ci = k{crow(2i,hi), crow(2i+1,hi)}
                    unsigned c0 = pk2(s[0],  s[1]),  c1 = pk2(s[2],  s[3]);
                    unsigned c2 = pk2(s[4],  s[5]),  c3 = pk2(s[6],  s[7]);
                    unsigned c4 = pk2(s[8],  s[9]),  c5 = pk2(s[10], s[11]);
                    unsigned c6 = pk2(s[12], s[13]), c7 = pk2(s[14], s[15]);
                    unsigned x0 = __shfl_xor((int)c0, 32), x1 = __shfl_xor((int)c1, 32);
                    unsigned x2 = __shfl_xor((int)c2, 32), x3 = __shfl_xor((int)c3, 32);
                    unsigned x4 = __shfl_xor((int)c4, 32), x5 = __shfl_xor((int)c5, 32);
                    unsigned x6 = __shfl_xor((int)c6, 32), x7 = __shfl_xor((int)c7, 32);
                    // pa0: k = hi*8 + j ; pa1: k = 16 + hi*8 + j
                    u32x4 w0 = { h ? x2 : c0, h ? x3 : c1, h ? c2 : x0, h ? c3 : x1 };
                    u32x4 w1 = { h ? x6 : c4, h ? x7 : c5, h ? c6 : x4, h ? c7 : x5 };
                    s16x8 pa0 = __builtin_bit_cast(s16x8, w0);
                    s16x8 pa1 = __builtin_bit_cast(s16x8, w1);

                    // --- PV: O += P * V  (b[j] = V^T[d][k]) ---
                    __builtin_amdgcn_s_setprio(1);
#pragma unroll
                    for (int ks = 0; ks < 2; ++ks) {
                        s16x8 pa = ks ? pa1 : pa0;
                        s16x8 bv0 = *(const s16x8*)&Vts[cur][(l31) * PAD + k2 * 32 + ks * 16 + hi * 8];
                        s16x8 bv1 = *(const s16x8*)&Vts[cur][(32 + l31) * PAD + k2 * 32 + ks * 16 + hi * 8];
                        o0 = mfma32(pa, bv0, o0);
                        o1 = mfma32(pa, bv1, o1);
                    }
                    __builtin_amdgcn_s_setprio(0);
                }
            }
            __syncthreads();
        }

        // ---- epilogue: divide by l, write O ----
        float il = 1.0f / lrow;
        xbuf[w][l31] = il;
        f32x4 ilv[4];
#pragma unroll
        for (int rr = 0; rr < 4; ++rr)
            ilv[rr] = *(const f32x4*)&xbuf[w][rr * 8 + hi * 4];
#pragma unroll
        for (int r = 0; r < 16; ++r) {
            int t = q0w + ((r & 3) + 8 * (r >> 2)) + 4 * hi;
            float sc = ilv[r >> 2][r & 3];
            long rbase = ((long)(bb * 2048 + t)) * 1024 + hh * 64;
            O[rbase + l31]      = f2bf(o0[r] * sc);
            O[rbase + 32 + l31] = f2bf(o1[r] * sc);
        }
        __syncthreads();   // protect LDS before next phase's prologue writes
    }
}

// ---------------------------------------------------------------------------
extern "C" void kernel_launch(void* const* d_in, const int* in_sizes, int n_in,
                              void* d_out, int out_size, void* d_ws, size_t ws_size,
                              hipStream_t stream)
{
    const float* x      = (const float*)d_in[0];
    const float* wq     = (const float*)d_in[1];
    const float* wk     = (const float*)d_in[2];
    const float* wv     = (const float*)d_in[3];
    const float* w_proj = (const float*)d_in[4];
    const float* b_proj = (const float*)d_in[5];
    const float* w1     = (const float*)d_in[6];
    const float* b1     = (const float*)d_in[7];
    const float* w2     = (const float*)d_in[8];
    const float* b2     = (const float*)d_in[9];
    const float* ln1_g  = (const float*)d_in[10];
    const float* ln1_b  = (const float*)d_in[11];
    const float* ln2_g  = (const float*)d_in[12];
    const float* ln2_b  = (const float*)d_in[13];

    char* ws = (char*)d_ws;
    u16*   WQKVt = (u16*)(ws + 0);           // 3072x1024 bf16
    u16*   WPt   = (u16*)(ws + 6291456);     // 1024x1024
    u16*   W1t   = (u16*)(ws + 8388608);     // 4096x1024
    u16*   W2t   = (u16*)(ws + 16777216);    // 1024x4096
    u16*   H     = (u16*)(ws + 25165824);    // 8192x1024 (h, then h2)
    u16*   Qb    = (u16*)(ws + 41943040);    // [B,H,T,D]
    u16*   Kb    = (u16*)(ws + 58720256);    // [B,H,T,D]
    u16*   Vb    = (u16*)(ws + 75497472);    // [B,H,D,T]  (transposed)
    u16*   Ob    = (u16*)(ws + 92274688);    // [B,T,C]
    u16*   FF    = (u16*)(ws + 41943040);    // 8192x4096, overlaps Q..O
    float* X1    = (float*)(ws + 109051904); // 8192x1024 fp32
    float* out   = (float*)d_out;

    transpose_cvt<<<dim3(16, 1, 16), 256, 0, stream>>>(wq, WQKVt,           1024, 64, 65536, 65536);
    transpose_cvt<<<dim3(16, 1, 16), 256, 0, stream>>>(wk, WQKVt + 1048576, 1024, 64, 65536, 65536);
    transpose_cvt<<<dim3(16, 1, 16), 256, 0, stream>>>(wv, WQKVt + 2097152, 1024, 64, 65536, 65536);
    transpose_cvt<<<dim3(16, 16, 1), 256, 0, stream>>>(w_proj, WPt, 1024, 1024, 0, 0);
    transpose_cvt<<<dim3(16, 64, 1), 256, 0, stream>>>(w1, W1t, 1024, 4096, 0, 0);
    transpose_cvt<<<dim3(64, 16, 1), 256, 0, stream>>>(w2, W2t, 4096, 1024, 0, 0);

    ln_bf16<<<8192, 256, 0, stream>>>(x, ln1_g, ln1_b, H);

    gemm_bt<0><<<dim3(64, 24), 256, 0, stream>>>(H, WQKVt, 8192, 3072, 1024,
        nullptr, nullptr, nullptr, nullptr, Qb, Kb, Vb);

    attn_kernel<<<dim3(8, 16, 4), 256, 0, stream>>>(Qb, Kb, Vb, Ob);

    gemm_bt<1><<<dim3(64, 8), 256, 0, stream>>>(Ob, WPt, 8192, 1024, 1024,
        X1, nullptr, b_proj, x, nullptr, nullptr, nullptr);

    ln_bf16<<<8192, 256, 0, stream>>>(X1, ln2_g, ln2_b, H);

    gemm_bt<2><<<dim3(64, 32), 256, 0, stream>>>(H, W1t, 8192, 4096, 1024,
        nullptr, FF, b1, nullptr, nullptr, nullptr, nullptr);

    gemm_bt<1><<<dim3(64, 8), 256, 0, stream>>>(FF, W2t, 8192, 1024, 4096,
        out, nullptr, b2, X1, nullptr, nullptr, nullptr);
}